// Round 5
// baseline (4394.641 us; speedup 1.0000x reference)
//
#include <hip/hip_runtime.h>

#define BB 2048
#define EE 8
#define CC 100

typedef __attribute__((ext_vector_type(8))) short s16x8;
typedef __attribute__((ext_vector_type(4))) float f32x4;

__device__ inline ushort f2b(float f) {
    union { float f; unsigned u; } c; c.f = f;
    return (ushort)((c.u + 0x7fffu + ((c.u >> 16) & 1u)) >> 16);
}
__device__ inline float b2f(ushort h) {
    union { unsigned u; float f; } c; c.u = ((unsigned)h) << 16;
    return c.f;
}

// ---------------------------------------------------------------------------
// zero used workspace so every call starts from the identical state
// ---------------------------------------------------------------------------
__global__ __launch_bounds__(256) void zero_ws_kernel(int4* __restrict__ p, long n16)
{
    long i = (long)blockIdx.x * 256 + threadIdx.x;
    const long stride = (long)gridDim.x * 256;
    const int4 z = make_int4(0, 0, 0, 0);
    for (; i < n16; i += stride) p[i] = z;
}

// ---------------------------------------------------------------------------
// conv1: [2048,3,32,32] -> conv3x3+BN+ReLU+pool -> NHWC bf16 hi/lo [2048,16,16,64]
// ---------------------------------------------------------------------------
__global__ __launch_bounds__(256) void conv1_kernel(
    const float* __restrict__ x, const float* __restrict__ w,
    const float* __restrict__ cb, const float* __restrict__ g,
    const float* __restrict__ be, ushort* __restrict__ oh, ushort* __restrict__ ol)
{
    __shared__ float xs[3][34][34];
    __shared__ float wsm[64][28];
    __shared__ float sc_s[64], bi_s[64];

    const int b = blockIdx.x;
    const int tid = threadIdx.x;

    for (int i = tid; i < 3 * 34 * 34; i += 256) {
        int ci = i / (34 * 34);
        int r  = (i / 34) % 34;
        int c  = i % 34;
        float v = 0.f;
        if (r >= 1 && r <= 32 && c >= 1 && c <= 32)
            v = x[(((long)b * 3 + ci) * 32 + (r - 1)) * 32 + (c - 1)];
        xs[ci][r][c] = v;
    }
    for (int i = tid; i < 64 * 27; i += 256) {
        int co = i / 27, k = i % 27;
        wsm[co][k] = w[co * 27 + k];
    }
    if (tid < 64) {
        float s = g[tid] * 0.99999500003749969f;
        sc_s[tid] = s;
        bi_s[tid] = cb[tid] * s + be[tid];
    }
    __syncthreads();

    const int py = tid >> 4, px = tid & 15;
    float xr[3][4][4];
    #pragma unroll
    for (int ci = 0; ci < 3; ci++)
        #pragma unroll
        for (int r = 0; r < 4; r++)
            #pragma unroll
            for (int c = 0; c < 4; c++)
                xr[ci][r][c] = xs[ci][2 * py + r][2 * px + c];

    for (int co = 0; co < 64; co++) {
        float a0 = 0.f, a1 = 0.f, a2 = 0.f, a3 = 0.f;
        #pragma unroll
        for (int ci = 0; ci < 3; ci++)
            #pragma unroll
            for (int ky = 0; ky < 3; ky++)
                #pragma unroll
                for (int kx = 0; kx < 3; kx++) {
                    float wv = wsm[co][ci * 9 + ky * 3 + kx];
                    a0 += wv * xr[ci][ky][kx];
                    a1 += wv * xr[ci][ky][kx + 1];
                    a2 += wv * xr[ci][ky + 1][kx];
                    a3 += wv * xr[ci][ky + 1][kx + 1];
                }
        float s = sc_s[co], bb2 = bi_s[co];
        float v0 = fmaxf(a0 * s + bb2, 0.f);
        float v1 = fmaxf(a1 * s + bb2, 0.f);
        float v2 = fmaxf(a2 * s + bb2, 0.f);
        float v3 = fmaxf(a3 * s + bb2, 0.f);
        float v  = fmaxf(fmaxf(v0, v1), fmaxf(v2, v3));
        long o = (((long)b * 16 + py) * 16 + px) * 64 + co;
        ushort h = f2b(v);
        oh[o] = h;
        ol[o] = f2b(v - b2f(h));
    }
}

// ---------------------------------------------------------------------------
// prep: conv weights [CO][CI][3][3] fp32 -> [CO][s*CI+ci] bf16 hi/lo (GEMM-B)
// ---------------------------------------------------------------------------
__global__ void prep_convw(const float* __restrict__ w, ushort* __restrict__ oh,
                           ushort* __restrict__ ol, int CO, int CI)
{
    long total = (long)CO * CI * 9;
    long i = (long)blockIdx.x * 256 + threadIdx.x;
    if (i >= total) return;
    int co = (int)(i / (9 * CI));
    int rem = (int)(i % (9 * CI));
    int s = rem / CI, ci = rem % CI;
    float v = w[((long)co * CI + ci) * 9 + s];
    ushort h = f2b(v);
    long o = (long)co * (9 * CI) + (long)s * CI + ci;
    oh[o] = h;
    ol[o] = f2b(v - b2f(h));
}

// ---------------------------------------------------------------------------
// prep: [z][K][N] fp32 -> transposed [z][Npad][K] bf16 hi (+lo), zero-padded
// ---------------------------------------------------------------------------
template <bool SPLIT>
__global__ __launch_bounds__(256) void prep_wT(
    const float* __restrict__ in, ushort* __restrict__ oh, ushort* __restrict__ ol,
    int K, int N, int Npad)
{
    __shared__ float tile[32][33];
    const int b = blockIdx.z;
    in += (long)b * K * N;
    oh += (long)b * Npad * K;
    if (SPLIT) ol += (long)b * Npad * K;
    const int k0 = blockIdx.y * 32, n0 = blockIdx.x * 32;
    const int tx = threadIdx.x & 31, ty = threadIdx.x >> 5;
    for (int i = ty; i < 32; i += 8) {
        int k = k0 + i, n = n0 + tx;
        tile[i][tx] = (k < K && n < N) ? in[(long)k * N + n] : 0.f;
    }
    __syncthreads();
    for (int i = ty; i < 32; i += 8) {
        int n = n0 + i, k = k0 + tx;
        if (n < Npad && k < K) {
            float v = tile[tx][i];
            ushort h = f2b(v);
            oh[(long)n * K + k] = h;
            if (SPLIT) ol[(long)n * K + k] = f2b(v - b2f(h));
        }
    }
}

__global__ void prep_bias2(const float* __restrict__ a, const float* __restrict__ b,
                           float* __restrict__ o)
{
    int i = blockIdx.x * 256 + threadIdx.x;
    if (i < 2048) o[i] = a[i];
    else if (i < 4096) o[i] = b[i - 2048];
}

// ---------------------------------------------------------------------------
// mgemm: unified MFMA GEMM, 128x128 tile, BK=32, 4 waves, 4x4 16x16 frags,
// 2-phase reg-staged pipeline (prefetch next K-step during MFMA phase).
// ASRC 0: A = bf16 hi(/lo) [M][K].  ASRC 1: implicit im2col gather from
//   PRE-SPLIT NHWC bf16 hi/lo planes [nImg][S][S][CI], K = 9*CI (s-major).
// SPLIT: bf16x3 (AhBh + AhBl + AlBh).
// EPI 0: fp32 +bias(+relu)   1: bf16 +bias(+relu)   2: fp32 +bias masked
//     3: BN+ReLU+2x2maxpool -> NHWC bf16 hi/lo planes (S=16/8)
//     4: BN+ReLU+pool -> f bf16 hi/lo NCHW-flat (S=4)
// ---------------------------------------------------------------------------
template <int ASRC, int EPI, bool SPLIT, bool RELU, int S, int CI>
__global__ __launch_bounds__(256, 4) void mgemm(
    const ushort* __restrict__ Agh, const ushort* __restrict__ Agl,
    const ushort* __restrict__ Ah, const ushort* __restrict__ Al,
    const ushort* __restrict__ Bh, const ushort* __restrict__ Bl,
    const float* __restrict__ bias,
    const float* __restrict__ cbp, const float* __restrict__ gp,
    const float* __restrict__ bep,
    void* __restrict__ O1, ushort* __restrict__ O2,
    int M, int N, int K, int realN,
    long aStr, long bStr, long biasStr, long oStr)
{
    constexpr int BKp = 40;
    __shared__ ushort sAh[128 * BKp];
    __shared__ ushort sBh[128 * BKp];
    __shared__ ushort sAl[SPLIT ? 128 * BKp : 8];
    __shared__ ushort sBl[SPLIT ? 128 * BKp : 8];

    const int e = blockIdx.z;
    if constexpr (ASRC == 0) {
        Ah += (long)e * aStr;
        if (SPLIT) Al += (long)e * aStr;
    }
    Bh += (long)e * bStr;
    if (SPLIT) Bl += (long)e * bStr;
    bias += (long)e * biasStr;

    const int tid = threadIdx.x;
    const int bm = blockIdx.x * 128, bn = blockIdx.y * 128;
    const int lane = tid & 63, wid = tid >> 6;
    const int wm0 = (wid >> 1) * 64, wn0 = (wid & 1) * 64;
    const int l16 = lane & 15, gq = lane >> 4;
    const int koff = gq * 8;

    const int r0 = tid >> 2, cb = (tid & 3) * 8;     // ASRC0 + B staging
    const int sr = tid >> 1, scb = (tid & 1) * 16;   // ASRC1 staging

    int g_im = 0, g_y0 = 0, g_x0 = 0;
    if constexpr (ASRC == 1) {
        int p = bm + sr;
        g_im = p / (S * S);
        int rem = p % (S * S);
        g_y0 = rem / S;
        g_x0 = rem % S;
    }

    int4 rah0, rah1, ral0, ral1, rbh0, rbh1, rbl0, rbl1;

    auto loadT = [&](int k0) {
        if constexpr (ASRC == 1) {
            const int s = k0 / CI, ci0 = k0 % CI;
            const int yy = g_y0 + s / 3 - 1, xx = g_x0 + (s % 3) - 1;
            if (yy >= 0 && yy < S && xx >= 0 && xx < S) {
                const long base = (((long)g_im * S + yy) * S + xx) * CI + ci0 + scb;
                rah0 = *(const int4*)&Agh[base];
                rah1 = *(const int4*)&Agh[base + 8];
                ral0 = *(const int4*)&Agl[base];
                ral1 = *(const int4*)&Agl[base + 8];
            } else {
                rah0 = rah1 = ral0 = ral1 = make_int4(0, 0, 0, 0);
            }
        } else {
            rah0 = *(const int4*)&Ah[(long)(bm + r0) * K + k0 + cb];
            rah1 = *(const int4*)&Ah[(long)(bm + r0 + 64) * K + k0 + cb];
            if (SPLIT) {
                ral0 = *(const int4*)&Al[(long)(bm + r0) * K + k0 + cb];
                ral1 = *(const int4*)&Al[(long)(bm + r0 + 64) * K + k0 + cb];
            }
        }
        rbh0 = *(const int4*)&Bh[(long)(bn + r0) * K + k0 + cb];
        rbh1 = *(const int4*)&Bh[(long)(bn + r0 + 64) * K + k0 + cb];
        if (SPLIT) {
            rbl0 = *(const int4*)&Bl[(long)(bn + r0) * K + k0 + cb];
            rbl1 = *(const int4*)&Bl[(long)(bn + r0 + 64) * K + k0 + cb];
        }
    };

    auto writeT = [&]() {
        if constexpr (ASRC == 1) {
            int o = sr * BKp + scb;
            *(int4*)&sAh[o] = rah0; *(int4*)&sAh[o + 8] = rah1;
            *(int4*)&sAl[o] = ral0; *(int4*)&sAl[o + 8] = ral1;
        } else {
            int oa = r0 * BKp + cb;
            *(int4*)&sAh[oa] = rah0; *(int4*)&sAh[oa + 64 * BKp] = rah1;
            if (SPLIT) { *(int4*)&sAl[oa] = ral0; *(int4*)&sAl[oa + 64 * BKp] = ral1; }
        }
        int ob = r0 * BKp + cb;
        *(int4*)&sBh[ob] = rbh0; *(int4*)&sBh[ob + 64 * BKp] = rbh1;
        if (SPLIT) { *(int4*)&sBl[ob] = rbl0; *(int4*)&sBl[ob + 64 * BKp] = rbl1; }
    };

    f32x4 acc[4][4];
    #pragma unroll
    for (int i = 0; i < 4; ++i)
        #pragma unroll
        for (int j = 0; j < 4; ++j)
            acc[i][j] = (f32x4){0.f, 0.f, 0.f, 0.f};

    loadT(0);
    for (int k0 = 0; k0 < K; k0 += 32) {
        __syncthreads();
        writeT();
        if (k0 + 32 < K) loadT(k0 + 32);
        __syncthreads();

        s16x8 fa[4], fb[4], fal[4], fbl[4];
        #pragma unroll
        for (int i = 0; i < 4; ++i) {
            fa[i] = *(const s16x8*)&sAh[(wm0 + i * 16 + l16) * BKp + koff];
            fb[i] = *(const s16x8*)&sBh[(wn0 + i * 16 + l16) * BKp + koff];
            if (SPLIT) {
                fal[i] = *(const s16x8*)&sAl[(wm0 + i * 16 + l16) * BKp + koff];
                fbl[i] = *(const s16x8*)&sBl[(wn0 + i * 16 + l16) * BKp + koff];
            }
        }
        #pragma unroll
        for (int i = 0; i < 4; ++i)
            #pragma unroll
            for (int j = 0; j < 4; ++j) {
                acc[i][j] = __builtin_amdgcn_mfma_f32_16x16x32_bf16(fa[i], fb[j], acc[i][j], 0, 0, 0);
                if (SPLIT) {
                    acc[i][j] = __builtin_amdgcn_mfma_f32_16x16x32_bf16(fa[i],  fbl[j], acc[i][j], 0, 0, 0);
                    acc[i][j] = __builtin_amdgcn_mfma_f32_16x16x32_bf16(fal[i], fb[j],  acc[i][j], 0, 0, 0);
                }
            }
    }

    if constexpr (EPI == 3) {
        const int pbase = bm + wm0;
        if constexpr (S == 16) {
            const int im = pbase / 256;
            const int yb = (pbase % 256) / 16;
            #pragma unroll
            for (int ip = 0; ip < 2; ++ip)
                #pragma unroll
                for (int j = 0; j < 4; ++j) {
                    const int n = bn + wn0 + j * 16 + l16;
                    const float sc = gp[n] * 0.99999500003749969f;
                    const float bi = cbp[n] * sc + bep[n];
                    #pragma unroll
                    for (int rp = 0; rp < 2; ++rp) {
                        float a00 = fmaxf(acc[2*ip][j][2*rp]     * sc + bi, 0.f);
                        float a01 = fmaxf(acc[2*ip][j][2*rp + 1] * sc + bi, 0.f);
                        float a10 = fmaxf(acc[2*ip+1][j][2*rp]     * sc + bi, 0.f);
                        float a11 = fmaxf(acc[2*ip+1][j][2*rp + 1] * sc + bi, 0.f);
                        float pv = fmaxf(fmaxf(a00, a01), fmaxf(a10, a11));
                        const int py = yb / 2 + ip;
                        const int px = gq * 2 + rp;
                        long idx = ((long)(im * 8 + py) * 8 + px) * N + n;
                        ushort h = f2b(pv);
                        ((ushort*)O1)[idx] = h;
                        O2[idx] = f2b(pv - b2f(h));
                    }
                }
        } else {  // S == 8
            const int im = pbase / 64;
            #pragma unroll
            for (int i = 0; i < 4; ++i)
                #pragma unroll
                for (int j = 0; j < 4; ++j) {
                    const int n = bn + wn0 + j * 16 + l16;
                    const float sc = gp[n] * 0.99999500003749969f;
                    const float bi = cbp[n] * sc + bep[n];
                    #pragma unroll
                    for (int rp = 0; rp < 2; ++rp) {
                        float xa = fmaxf(acc[i][j][2*rp]     * sc + bi, 0.f);
                        float xb = fmaxf(acc[i][j][2*rp + 1] * sc + bi, 0.f);
                        float xm = fmaxf(xa, xb);
                        float ym = fmaxf(xm, __shfl_xor(xm, 32));
                        if (lane < 32) {
                            const int py = i, px = (gq & 1) * 2 + rp;
                            long idx = ((long)(im * 4 + py) * 4 + px) * N + n;
                            ushort h = f2b(ym);
                            ((ushort*)O1)[idx] = h;
                            O2[idx] = f2b(ym - b2f(h));
                        }
                    }
                }
        }
    } else if constexpr (EPI == 4) {
        const int pbase = bm + wm0;
        const int im0 = pbase / 16;
        #pragma unroll
        for (int i = 0; i < 4; ++i)
            #pragma unroll
            for (int j = 0; j < 4; ++j) {
                const int n = bn + wn0 + j * 16 + l16;
                const float sc = gp[n] * 0.99999500003749969f;
                const float bi = cbp[n] * sc + bep[n];
                #pragma unroll
                for (int rp = 0; rp < 2; ++rp) {
                    float xa = fmaxf(acc[i][j][2*rp]     * sc + bi, 0.f);
                    float xb = fmaxf(acc[i][j][2*rp + 1] * sc + bi, 0.f);
                    float xm = fmaxf(xa, xb);
                    float ym = fmaxf(xm, __shfl_xor(xm, 16));
                    if ((gq & 1) == 0) {
                        const int py = gq >> 1, px = rp;
                        const long fi = (long)(im0 + i) * 2048 + (long)n * 4 + py * 2 + px;
                        ushort h = f2b(ym);
                        ((ushort*)O1)[fi] = h;
                        O2[fi] = f2b(ym - b2f(h));
                    }
                }
            }
    } else {
        #pragma unroll
        for (int i = 0; i < 4; ++i)
            #pragma unroll
            for (int j = 0; j < 4; ++j) {
                const int n = bn + wn0 + j * 16 + l16;
                const float bv = (n < realN) ? bias[n] : 0.f;
                #pragma unroll
                for (int r = 0; r < 4; ++r) {
                    const int m = bm + wm0 + i * 16 + gq * 4 + r;
                    float v = acc[i][j][r] + bv;
                    if (RELU) v = fmaxf(v, 0.f);
                    if constexpr (EPI == 1)
                        ((ushort*)O1 + (long)e * oStr)[(long)m * N + n] = f2b(v);
                    else
                        ((float*)O1 + (long)e * oStr)[(long)m * N + n] = v;
                }
            }
    }
}

// ---------------------------------------------------------------------------
// fused small GEMMs: clean[b][8], raw[b][8] from gh[b][4096]
// ---------------------------------------------------------------------------
__global__ __launch_bounds__(256) void small2_kernel(
    const float* __restrict__ gh, const float* __restrict__ wg2,
    const float* __restrict__ wg2b, const float* __restrict__ wn2,
    const float* __restrict__ wn2b, float* __restrict__ clean,
    float* __restrict__ rawp)
{
    const int b = blockIdx.x, tid = threadIdx.x;
    float ac[8] = {0,0,0,0,0,0,0,0}, ar[8] = {0,0,0,0,0,0,0,0};
    for (int k = tid; k < 2048; k += 256) {
        float a1 = gh[(long)b * 4096 + k];
        float a2 = gh[(long)b * 4096 + 2048 + k];
        const float4* w1 = (const float4*)&wg2[(long)k * 8];
        float4 p = w1[0], q = w1[1];
        ac[0] += a1 * p.x; ac[1] += a1 * p.y; ac[2] += a1 * p.z; ac[3] += a1 * p.w;
        ac[4] += a1 * q.x; ac[5] += a1 * q.y; ac[6] += a1 * q.z; ac[7] += a1 * q.w;
        const float4* w2 = (const float4*)&wn2[(long)k * 8];
        p = w2[0]; q = w2[1];
        ar[0] += a2 * p.x; ar[1] += a2 * p.y; ar[2] += a2 * p.z; ar[3] += a2 * p.w;
        ar[4] += a2 * q.x; ar[5] += a2 * q.y; ar[6] += a2 * q.z; ar[7] += a2 * q.w;
    }
    __shared__ float red[256][16];
    #pragma unroll
    for (int e2 = 0; e2 < 8; e2++) { red[tid][e2] = ac[e2]; red[tid][8 + e2] = ar[e2]; }
    __syncthreads();
    for (int s = 128; s > 0; s >>= 1) {
        if (tid < s)
            #pragma unroll
            for (int e2 = 0; e2 < 16; e2++) red[tid][e2] += red[tid + s][e2];
        __syncthreads();
    }
    if (tid < 8) clean[(long)b * 8 + tid] = red[0][tid] + wg2b[tid];
    else if (tid < 16) rawp[(long)b * 8 + tid - 8] = red[0][tid] + wn2b[tid - 8];
}

// ---------------------------------------------------------------------------
// gating: noisy top-k, softmax over top-K, gates, prob/load partials
// ---------------------------------------------------------------------------
__global__ __launch_bounds__(256) void gate_kernel(
    const float* __restrict__ clean, const float* __restrict__ raw,
    const float* __restrict__ noise, float* __restrict__ gates,
    float* __restrict__ part)
{
    __shared__ float red[256][8];
    const int tid = threadIdx.x;
    const int b = blockIdx.x * 256 + tid;

    float cl[8], st[8], ny[8];
    #pragma unroll
    for (int e2 = 0; e2 < 8; e2++) {
        cl[e2] = clean[(long)b * 8 + e2];
        float r = raw[(long)b * 8 + e2];
        st[e2] = fmaxf(r, 0.f) + log1pf(expf(-fabsf(r))) + 0.01f;
        ny[e2] = cl[e2] + noise[(long)b * 8 + e2] * st[e2];
    }
    float v0 = -3e38f, v1 = -3e38f, v2 = -3e38f;
    int i0 = 0, i1 = 0;
    #pragma unroll
    for (int e2 = 0; e2 < 8; e2++) {
        float xv = ny[e2];
        if (xv > v0)      { v2 = v1; v1 = v0; i1 = i0; v0 = xv; i0 = e2; }
        else if (xv > v1) { v2 = v1; v1 = xv; i1 = e2; }
        else if (xv > v2) { v2 = xv; }
    }
    float e1 = expf(v1 - v0);
    float z  = 1.f + e1;
    float g0 = 1.f / z, g1 = e1 / z;

    const float inv_sqrt2 = 0.70710678118654752f;
    float grow[8], prob[8];
    #pragma unroll
    for (int e2 = 0; e2 < 8; e2++) {
        grow[e2] = (e2 == i0) ? g0 : ((e2 == i1) ? g1 : 0.f);
        float th = (ny[e2] > v2) ? v2 : v1;
        float zz = (cl[e2] - th) / st[e2];
        prob[e2] = 0.5f * (1.f + erff(zz * inv_sqrt2));
        gates[(long)b * 8 + e2] = grow[e2];
    }
    #pragma unroll
    for (int e2 = 0; e2 < 8; e2++) red[tid][e2] = grow[e2];
    __syncthreads();
    for (int s = 128; s > 0; s >>= 1) {
        if (tid < s)
            #pragma unroll
            for (int e2 = 0; e2 < 8; e2++) red[tid][e2] += red[tid + s][e2];
        __syncthreads();
    }
    if (tid < 8) part[blockIdx.x * 16 + tid] = red[0][tid];
    __syncthreads();
    #pragma unroll
    for (int e2 = 0; e2 < 8; e2++) red[tid][e2] = prob[e2];
    __syncthreads();
    for (int s = 128; s > 0; s >>= 1) {
        if (tid < s)
            #pragma unroll
            for (int e2 = 0; e2 < 8; e2++) red[tid][e2] += red[tid + s][e2];
        __syncthreads();
    }
    if (tid < 8) part[blockIdx.x * 16 + 8 + tid] = red[0][tid];
}

__global__ void loss_kernel(const float* __restrict__ part, float* __restrict__ lossp)
{
    if (threadIdx.x == 0) {
        float imp[8], ld[8];
        for (int e2 = 0; e2 < 8; e2++) { imp[e2] = 0.f; ld[e2] = 0.f; }
        for (int blk = 0; blk < 8; blk++)
            for (int e2 = 0; e2 < 8; e2++) {
                imp[e2] += part[blk * 16 + e2];
                ld[e2]  += part[blk * 16 + 8 + e2];
            }
        float mi = 0.f, ml = 0.f;
        for (int e2 = 0; e2 < 8; e2++) { mi += imp[e2]; ml += ld[e2]; }
        mi *= 0.125f; ml *= 0.125f;
        float vi = 0.f, vl = 0.f;
        for (int e2 = 0; e2 < 8; e2++) {
            vi += (imp[e2] - mi) * (imp[e2] - mi);
            vl += (ld[e2] - ml) * (ld[e2] - ml);
        }
        vi /= 7.f; vl /= 7.f;
        lossp[0] = vi / (mi * mi + 1e-10f) + vl / (ml * ml + 1e-10f);
    }
}

__global__ void combine_kernel(const float* __restrict__ gates,
                               const float* __restrict__ eo, float* __restrict__ y)
{
    const int idx = blockIdx.x * 256 + threadIdx.x;
    if (idx >= BB * CC) return;
    const int b = idx / CC, c = idx % CC;
    float s = 0.f;
    #pragma unroll
    for (int e2 = 0; e2 < 8; e2++)
        s += gates[(long)b * 8 + e2] * eo[((long)e2 * BB + b) * 128 + c];
    y[idx] = s;
}

// ---------------------------------------------------------------------------
// launch
// ---------------------------------------------------------------------------
extern "C" void kernel_launch(void* const* d_in, const int* in_sizes, int n_in,
                              void* d_out, int out_size, void* d_ws, size_t ws_size,
                              hipStream_t stream)
{
    const float* x     = (const float*)d_in[0];
    const float* noise = (const float*)d_in[1];
    const float* cw1 = (const float*)d_in[2];  const float* cb1 = (const float*)d_in[3];
    const float* g1  = (const float*)d_in[4];  const float* be1 = (const float*)d_in[5];
    const float* cw2 = (const float*)d_in[6];  const float* cb2 = (const float*)d_in[7];
    const float* g2  = (const float*)d_in[8];  const float* be2 = (const float*)d_in[9];
    const float* cw3 = (const float*)d_in[10]; const float* cb3 = (const float*)d_in[11];
    const float* g3  = (const float*)d_in[12]; const float* be3 = (const float*)d_in[13];
    const float* cw4 = (const float*)d_in[14]; const float* cb4 = (const float*)d_in[15];
    const float* g4  = (const float*)d_in[16]; const float* be4 = (const float*)d_in[17];
    const float* wg1 = (const float*)d_in[18]; const float* wg1b = (const float*)d_in[19];
    const float* wg2 = (const float*)d_in[20]; const float* wg2b = (const float*)d_in[21];
    const float* wn1 = (const float*)d_in[22]; const float* wn1b = (const float*)d_in[23];
    const float* wn2 = (const float*)d_in[24]; const float* wn2b = (const float*)d_in[25];
    const float* eW1 = (const float*)d_in[26]; const float* eb1 = (const float*)d_in[27];
    const float* eW2 = (const float*)d_in[28]; const float* eb2 = (const float*)d_in[29];
    const float* eW3 = (const float*)d_in[30]; const float* eb3 = (const float*)d_in[31];

    float* out = (float*)d_out;
    char*  W   = (char*)d_ws;

    // ---- workspace layout (bytes), lifetime-overlaid, ~217 MB ----
    ushort* c2h   = (ushort*)(W + 0);              // [2048,16,16,64] hi (67.1MB)
    ushort* c2l   = (ushort*)(W + 67108864);       //                 lo
    ushort* c3h   = (ushort*)(W + 134217728);      // [2048,8,8,128] hi (33.5MB)
    ushort* c3l   = (ushort*)(W + 167772160);      //                 lo (ends 201326592)
    ushort* c4h   = (ushort*)(W + 0);              // [2048,4,4,256] hi (16.8MB, after conv3)
    ushort* c4l   = (ushort*)(W + 16777216);       //                 lo (ends 33554432)
    ushort* fh    = (ushort*)(W + 33554432);       // [2048,2048] bf16 hi
    ushort* fl    = (ushort*)(W + 41943040);       //              bf16 lo
    ushort* wTh   = (ushort*)(W + 50331648);       // [4096,2048] gating W^T hi (after conv2)
    ushort* wTl   = (ushort*)(W + 67108864);       //              lo
    float*  bias4096 = (float*)(W + 83886080);
    float*  gh    = (float*) (W + 83902464);       // [2048,4096] fp32 (ends 117456896)
    float*  clean = (float*) (W + 117456896);
    float*  rawp  = (float*) (W + 117522432);
    float*  gates = (float*) (W + 117587968);
    float*  part  = (float*) (W + 117653504);
    ushort* eW1T  = (ushort*)(W + 134217728);      // [8,1024,2048] (after conv3)
    ushort* eW2T  = (ushort*)(W + 167772160);      // [8,512,1024]
    ushort* eW3T  = (ushort*)(W + 176160768);      // [8,128,512]
    ushort* eh1   = (ushort*)(W + 177209344);      // [8,2048,1024] bf16 (ends 210763776)
    ushort* eh2   = (ushort*)(W + 83902464);       // [8,2048,512] bf16 (gh region, after small2)
    float*  eo    = (float*) (W + 0);              // [8,2048,128] fp32 (after conv4)
    ushort* bc2h  = (ushort*)(W + 210763776);      // conv-B packs
    ushort* bc2l  = (ushort*)(W + 210911232);
    ushort* bc3h  = (ushort*)(W + 211058688);
    ushort* bc3l  = (ushort*)(W + 211648512);
    ushort* bc4h  = (ushort*)(W + 212238336);
    ushort* bc4l  = (ushort*)(W + 214597632);      // ends 216956928

    // ---- zero used workspace (identical state every call) ----
    {
        long used = 216956928;
        long cap = (ws_size < (size_t)used) ? (long)ws_size : used;
        zero_ws_kernel<<<2048, 256, 0, stream>>>((int4*)d_ws, cap / 16);
    }

    // ---- conv weight packs ----
    prep_convw<<<(9 * 128 * 64 + 255) / 256, 256, 0, stream>>>(cw2, bc2h, bc2l, 128, 64);
    prep_convw<<<(9 * 256 * 128 + 255) / 256, 256, 0, stream>>>(cw3, bc3h, bc3l, 256, 128);
    prep_convw<<<(9 * 512 * 256 + 255) / 256, 256, 0, stream>>>(cw4, bc4h, bc4l, 512, 256);

    // ---- CNN ----
    conv1_kernel<<<2048, 256, 0, stream>>>(x, cw1, cb1, g1, be1, c2h, c2l);
    // conv2: M=524288, N=128, K=576
    mgemm<1, 3, true, false, 16, 64><<<dim3(4096, 1), 256, 0, stream>>>(
        c2h, c2l, nullptr, nullptr, bc2h, bc2l, nullptr, cb2, g2, be2,
        c3h, c3l, 524288, 128, 576, 128, 0, 0, 0, 0);

    // gating weight prep (c2 region now dead)
    prep_wT<true><<<dim3(64, 64, 1), 256, 0, stream>>>(wg1, wTh, wTl, 2048, 2048, 2048);
    prep_wT<true><<<dim3(64, 64, 1), 256, 0, stream>>>(wn1, wTh + 4194304, wTl + 4194304, 2048, 2048, 2048);
    prep_bias2<<<16, 256, 0, stream>>>(wg1b, wn1b, bias4096);

    // conv3: M=131072, N=256, K=1152
    mgemm<1, 3, true, false, 8, 128><<<dim3(1024, 2), 256, 0, stream>>>(
        c3h, c3l, nullptr, nullptr, bc3h, bc3l, nullptr, cb3, g3, be3,
        c4h, c4l, 131072, 256, 1152, 256, 0, 0, 0, 0);

    // expert weight prep (c3 region now dead)
    prep_wT<false><<<dim3(32, 64, 8), 256, 0, stream>>>(eW1, eW1T, nullptr, 2048, 1024, 1024);
    prep_wT<false><<<dim3(16, 32, 8), 256, 0, stream>>>(eW2, eW2T, nullptr, 1024, 512, 512);
    prep_wT<false><<<dim3(4, 16, 8), 256, 0, stream>>>(eW3, eW3T, nullptr, 512, 100, 128);

    // conv4: M=32768, N=512, K=2304 -> f hi/lo
    mgemm<1, 4, true, false, 4, 256><<<dim3(256, 4), 256, 0, stream>>>(
        c4h, c4l, nullptr, nullptr, bc4h, bc4l, nullptr, cb4, g4, be4,
        fh, fl, 32768, 512, 2304, 512, 0, 0, 0, 0);

    // ---- gating trunk (fused wg1|wn1, bf16x3) ----
    mgemm<0, 0, true, true, 1, 1><<<dim3(16, 32, 1), 256, 0, stream>>>(
        nullptr, nullptr, fh, fl, wTh, wTl, bias4096, nullptr, nullptr, nullptr,
        gh, nullptr, 2048, 4096, 2048, 4096, 0, 0, 0, 0);
    small2_kernel<<<BB, 256, 0, stream>>>(gh, wg2, wg2b, wn2, wn2b, clean, rawp);
    gate_kernel<<<8, 256, 0, stream>>>(clean, rawp, noise, gates, part);
    loss_kernel<<<1, 64, 0, stream>>>(part, out + (long)BB * CC);

    // ---- experts (plain bf16) ----
    mgemm<0, 1, false, true, 1, 1><<<dim3(16, 8, 8), 256, 0, stream>>>(
        nullptr, nullptr, fh, nullptr, eW1T, nullptr, eb1, nullptr, nullptr, nullptr,
        eh1, nullptr, 2048, 1024, 2048, 1024, 0, (long)1024 * 2048, 1024, (long)2048 * 1024);
    mgemm<0, 1, false, true, 1, 1><<<dim3(16, 4, 8), 256, 0, stream>>>(
        nullptr, nullptr, eh1, nullptr, eW2T, nullptr, eb2, nullptr, nullptr, nullptr,
        eh2, nullptr, 2048, 512, 1024, 512, (long)2048 * 1024, (long)512 * 1024, 512, (long)2048 * 512);
    mgemm<0, 2, false, false, 1, 1><<<dim3(16, 1, 8), 256, 0, stream>>>(
        nullptr, nullptr, eh2, nullptr, eW3T, nullptr, eb3, nullptr, nullptr, nullptr,
        eo, nullptr, 2048, 128, 512, 100, (long)2048 * 512, (long)128 * 512, 100, (long)2048 * 128);

    // ---- combine ----
    combine_kernel<<<(BB * CC + 255) / 256, 256, 0, stream>>>(gates, eo, out);
}

// Round 6
// 2132.157 us; speedup vs baseline: 2.0611x; 2.0611x over previous
//
#include <hip/hip_runtime.h>

#define BB 2048
#define EE 8
#define CC 100

typedef __attribute__((ext_vector_type(8))) short s16x8;
typedef __attribute__((ext_vector_type(4))) float f32x4;

__device__ inline ushort f2b(float f) {
    union { float f; unsigned u; } c; c.f = f;
    return (ushort)((c.u + 0x7fffu + ((c.u >> 16) & 1u)) >> 16);
}
__device__ inline float b2f(ushort h) {
    union { unsigned u; float f; } c; c.u = ((unsigned)h) << 16;
    return c.f;
}

// ---------------------------------------------------------------------------
// zero used workspace so every call starts from the identical state
// ---------------------------------------------------------------------------
__global__ __launch_bounds__(256) void zero_ws_kernel(int4* __restrict__ p, long n16)
{
    long i = (long)blockIdx.x * 256 + threadIdx.x;
    const long stride = (long)gridDim.x * 256;
    const int4 z = make_int4(0, 0, 0, 0);
    for (; i < n16; i += stride) p[i] = z;
}

// ---------------------------------------------------------------------------
// conv1: [2048,3,32,32] -> conv3x3+BN+ReLU+pool -> NHWC bf16 hi/lo [2048,16,16,64]
// ---------------------------------------------------------------------------
__global__ __launch_bounds__(256) void conv1_kernel(
    const float* __restrict__ x, const float* __restrict__ w,
    const float* __restrict__ cb, const float* __restrict__ g,
    const float* __restrict__ be, ushort* __restrict__ oh, ushort* __restrict__ ol)
{
    __shared__ float xs[3][34][34];
    __shared__ float wsm[64][28];
    __shared__ float sc_s[64], bi_s[64];

    const int b = blockIdx.x;
    const int tid = threadIdx.x;

    for (int i = tid; i < 3 * 34 * 34; i += 256) {
        int ci = i / (34 * 34);
        int r  = (i / 34) % 34;
        int c  = i % 34;
        float v = 0.f;
        if (r >= 1 && r <= 32 && c >= 1 && c <= 32)
            v = x[(((long)b * 3 + ci) * 32 + (r - 1)) * 32 + (c - 1)];
        xs[ci][r][c] = v;
    }
    for (int i = tid; i < 64 * 27; i += 256) {
        int co = i / 27, k = i % 27;
        wsm[co][k] = w[co * 27 + k];
    }
    if (tid < 64) {
        float s = g[tid] * 0.99999500003749969f;
        sc_s[tid] = s;
        bi_s[tid] = cb[tid] * s + be[tid];
    }
    __syncthreads();

    const int py = tid >> 4, px = tid & 15;
    float xr[3][4][4];
    #pragma unroll
    for (int ci = 0; ci < 3; ci++)
        #pragma unroll
        for (int r = 0; r < 4; r++)
            #pragma unroll
            for (int c = 0; c < 4; c++)
                xr[ci][r][c] = xs[ci][2 * py + r][2 * px + c];

    for (int co = 0; co < 64; co++) {
        float a0 = 0.f, a1 = 0.f, a2 = 0.f, a3 = 0.f;
        #pragma unroll
        for (int ci = 0; ci < 3; ci++)
            #pragma unroll
            for (int ky = 0; ky < 3; ky++)
                #pragma unroll
                for (int kx = 0; kx < 3; kx++) {
                    float wv = wsm[co][ci * 9 + ky * 3 + kx];
                    a0 += wv * xr[ci][ky][kx];
                    a1 += wv * xr[ci][ky][kx + 1];
                    a2 += wv * xr[ci][ky + 1][kx];
                    a3 += wv * xr[ci][ky + 1][kx + 1];
                }
        float s = sc_s[co], bb2 = bi_s[co];
        float v0 = fmaxf(a0 * s + bb2, 0.f);
        float v1 = fmaxf(a1 * s + bb2, 0.f);
        float v2 = fmaxf(a2 * s + bb2, 0.f);
        float v3 = fmaxf(a3 * s + bb2, 0.f);
        float v  = fmaxf(fmaxf(v0, v1), fmaxf(v2, v3));
        long o = (((long)b * 16 + py) * 16 + px) * 64 + co;
        ushort h = f2b(v);
        oh[o] = h;
        ol[o] = f2b(v - b2f(h));
    }
}

// ---------------------------------------------------------------------------
// prep: conv weights [CO][CI][3][3] fp32 -> [CO][s*CI+ci] bf16 hi/lo (GEMM-B)
// ---------------------------------------------------------------------------
__global__ void prep_convw(const float* __restrict__ w, ushort* __restrict__ oh,
                           ushort* __restrict__ ol, int CO, int CI)
{
    long total = (long)CO * CI * 9;
    long i = (long)blockIdx.x * 256 + threadIdx.x;
    if (i >= total) return;
    int co = (int)(i / (9 * CI));
    int rem = (int)(i % (9 * CI));
    int s = rem / CI, ci = rem % CI;
    float v = w[((long)co * CI + ci) * 9 + s];
    ushort h = f2b(v);
    long o = (long)co * (9 * CI) + (long)s * CI + ci;
    oh[o] = h;
    ol[o] = f2b(v - b2f(h));
}

// ---------------------------------------------------------------------------
// prep: [z][K][N] fp32 -> transposed [z][Npad][K] bf16 hi (+lo), zero-padded
// ---------------------------------------------------------------------------
template <bool SPLIT>
__global__ __launch_bounds__(256) void prep_wT(
    const float* __restrict__ in, ushort* __restrict__ oh, ushort* __restrict__ ol,
    int K, int N, int Npad)
{
    __shared__ float tile[32][33];
    const int b = blockIdx.z;
    in += (long)b * K * N;
    oh += (long)b * Npad * K;
    if (SPLIT) ol += (long)b * Npad * K;
    const int k0 = blockIdx.y * 32, n0 = blockIdx.x * 32;
    const int tx = threadIdx.x & 31, ty = threadIdx.x >> 5;
    for (int i = ty; i < 32; i += 8) {
        int k = k0 + i, n = n0 + tx;
        tile[i][tx] = (k < K && n < N) ? in[(long)k * N + n] : 0.f;
    }
    __syncthreads();
    for (int i = ty; i < 32; i += 8) {
        int n = n0 + i, k = k0 + tx;
        if (n < Npad && k < K) {
            float v = tile[tx][i];
            ushort h = f2b(v);
            oh[(long)n * K + k] = h;
            if (SPLIT) ol[(long)n * K + k] = f2b(v - b2f(h));
        }
    }
}

__global__ void prep_bias2(const float* __restrict__ a, const float* __restrict__ b,
                           float* __restrict__ o)
{
    int i = blockIdx.x * 256 + threadIdx.x;
    if (i < 2048) o[i] = a[i];
    else if (i < 4096) o[i] = b[i - 2048];
}

// ---------------------------------------------------------------------------
// mgemm: unified MFMA GEMM, 128x128 tile, BK=32, 4 waves, 4x4 16x16 frags,
// 2-phase reg-staged pipeline (prefetch next K-step during MFMA phase).
// NOTE: no min-waves launch bound — (256,4) capped VGPR at 64 and spilled
// acc+prefetch to scratch (5 GB/dispatch HBM traffic, 2.6x regression, R5).
// ---------------------------------------------------------------------------
template <int ASRC, int EPI, bool SPLIT, bool RELU, int S, int CI>
__global__ __launch_bounds__(256) void mgemm(
    const ushort* __restrict__ Agh, const ushort* __restrict__ Agl,
    const ushort* __restrict__ Ah, const ushort* __restrict__ Al,
    const ushort* __restrict__ Bh, const ushort* __restrict__ Bl,
    const float* __restrict__ bias,
    const float* __restrict__ cbp, const float* __restrict__ gp,
    const float* __restrict__ bep,
    void* __restrict__ O1, ushort* __restrict__ O2,
    int M, int N, int K, int realN,
    long aStr, long bStr, long biasStr, long oStr)
{
    constexpr int BKp = 40;
    __shared__ ushort sAh[128 * BKp];
    __shared__ ushort sBh[128 * BKp];
    __shared__ ushort sAl[SPLIT ? 128 * BKp : 8];
    __shared__ ushort sBl[SPLIT ? 128 * BKp : 8];

    const int e = blockIdx.z;
    if constexpr (ASRC == 0) {
        Ah += (long)e * aStr;
        if (SPLIT) Al += (long)e * aStr;
    }
    Bh += (long)e * bStr;
    if (SPLIT) Bl += (long)e * bStr;
    bias += (long)e * biasStr;

    const int tid = threadIdx.x;
    const int bm = blockIdx.x * 128, bn = blockIdx.y * 128;
    const int lane = tid & 63, wid = tid >> 6;
    const int wm0 = (wid >> 1) * 64, wn0 = (wid & 1) * 64;
    const int l16 = lane & 15, gq = lane >> 4;
    const int koff = gq * 8;

    const int r0 = tid >> 2, cb = (tid & 3) * 8;     // ASRC0 + B staging
    const int sr = tid >> 1, scb = (tid & 1) * 16;   // ASRC1 staging

    int g_im = 0, g_y0 = 0, g_x0 = 0;
    if constexpr (ASRC == 1) {
        int p = bm + sr;
        g_im = p / (S * S);
        int rem = p % (S * S);
        g_y0 = rem / S;
        g_x0 = rem % S;
    }

    int4 rah0, rah1, ral0, ral1, rbh0, rbh1, rbl0, rbl1;

    auto loadT = [&](int k0) {
        if constexpr (ASRC == 1) {
            const int s = k0 / CI, ci0 = k0 % CI;
            const int yy = g_y0 + s / 3 - 1, xx = g_x0 + (s % 3) - 1;
            if (yy >= 0 && yy < S && xx >= 0 && xx < S) {
                const long base = (((long)g_im * S + yy) * S + xx) * CI + ci0 + scb;
                rah0 = *(const int4*)&Agh[base];
                rah1 = *(const int4*)&Agh[base + 8];
                ral0 = *(const int4*)&Agl[base];
                ral1 = *(const int4*)&Agl[base + 8];
            } else {
                rah0 = rah1 = ral0 = ral1 = make_int4(0, 0, 0, 0);
            }
        } else {
            rah0 = *(const int4*)&Ah[(long)(bm + r0) * K + k0 + cb];
            rah1 = *(const int4*)&Ah[(long)(bm + r0 + 64) * K + k0 + cb];
            if (SPLIT) {
                ral0 = *(const int4*)&Al[(long)(bm + r0) * K + k0 + cb];
                ral1 = *(const int4*)&Al[(long)(bm + r0 + 64) * K + k0 + cb];
            }
        }
        rbh0 = *(const int4*)&Bh[(long)(bn + r0) * K + k0 + cb];
        rbh1 = *(const int4*)&Bh[(long)(bn + r0 + 64) * K + k0 + cb];
        if (SPLIT) {
            rbl0 = *(const int4*)&Bl[(long)(bn + r0) * K + k0 + cb];
            rbl1 = *(const int4*)&Bl[(long)(bn + r0 + 64) * K + k0 + cb];
        }
    };

    auto writeT = [&]() {
        if constexpr (ASRC == 1) {
            int o = sr * BKp + scb;
            *(int4*)&sAh[o] = rah0; *(int4*)&sAh[o + 8] = rah1;
            *(int4*)&sAl[o] = ral0; *(int4*)&sAl[o + 8] = ral1;
        } else {
            int oa = r0 * BKp + cb;
            *(int4*)&sAh[oa] = rah0; *(int4*)&sAh[oa + 64 * BKp] = rah1;
            if (SPLIT) { *(int4*)&sAl[oa] = ral0; *(int4*)&sAl[oa + 64 * BKp] = ral1; }
        }
        int ob = r0 * BKp + cb;
        *(int4*)&sBh[ob] = rbh0; *(int4*)&sBh[ob + 64 * BKp] = rbh1;
        if (SPLIT) { *(int4*)&sBl[ob] = rbl0; *(int4*)&sBl[ob + 64 * BKp] = rbl1; }
    };

    f32x4 acc[4][4];
    #pragma unroll
    for (int i = 0; i < 4; ++i)
        #pragma unroll
        for (int j = 0; j < 4; ++j)
            acc[i][j] = (f32x4){0.f, 0.f, 0.f, 0.f};

    loadT(0);
    for (int k0 = 0; k0 < K; k0 += 32) {
        __syncthreads();
        writeT();
        if (k0 + 32 < K) loadT(k0 + 32);
        __syncthreads();

        s16x8 fa[4], fb[4], fal[4], fbl[4];
        #pragma unroll
        for (int i = 0; i < 4; ++i) {
            fa[i] = *(const s16x8*)&sAh[(wm0 + i * 16 + l16) * BKp + koff];
            fb[i] = *(const s16x8*)&sBh[(wn0 + i * 16 + l16) * BKp + koff];
            if (SPLIT) {
                fal[i] = *(const s16x8*)&sAl[(wm0 + i * 16 + l16) * BKp + koff];
                fbl[i] = *(const s16x8*)&sBl[(wn0 + i * 16 + l16) * BKp + koff];
            }
        }
        #pragma unroll
        for (int i = 0; i < 4; ++i)
            #pragma unroll
            for (int j = 0; j < 4; ++j) {
                acc[i][j] = __builtin_amdgcn_mfma_f32_16x16x32_bf16(fa[i], fb[j], acc[i][j], 0, 0, 0);
                if (SPLIT) {
                    acc[i][j] = __builtin_amdgcn_mfma_f32_16x16x32_bf16(fa[i],  fbl[j], acc[i][j], 0, 0, 0);
                    acc[i][j] = __builtin_amdgcn_mfma_f32_16x16x32_bf16(fal[i], fb[j],  acc[i][j], 0, 0, 0);
                }
            }
    }

    if constexpr (EPI == 3) {
        const int pbase = bm + wm0;
        if constexpr (S == 16) {
            const int im = pbase / 256;
            const int yb = (pbase % 256) / 16;
            #pragma unroll
            for (int ip = 0; ip < 2; ++ip)
                #pragma unroll
                for (int j = 0; j < 4; ++j) {
                    const int n = bn + wn0 + j * 16 + l16;
                    const float sc = gp[n] * 0.99999500003749969f;
                    const float bi = cbp[n] * sc + bep[n];
                    #pragma unroll
                    for (int rp = 0; rp < 2; ++rp) {
                        float a00 = fmaxf(acc[2*ip][j][2*rp]     * sc + bi, 0.f);
                        float a01 = fmaxf(acc[2*ip][j][2*rp + 1] * sc + bi, 0.f);
                        float a10 = fmaxf(acc[2*ip+1][j][2*rp]     * sc + bi, 0.f);
                        float a11 = fmaxf(acc[2*ip+1][j][2*rp + 1] * sc + bi, 0.f);
                        float pv = fmaxf(fmaxf(a00, a01), fmaxf(a10, a11));
                        const int py = yb / 2 + ip;
                        const int px = gq * 2 + rp;
                        long idx = ((long)(im * 8 + py) * 8 + px) * N + n;
                        ushort h = f2b(pv);
                        ((ushort*)O1)[idx] = h;
                        O2[idx] = f2b(pv - b2f(h));
                    }
                }
        } else {  // S == 8
            const int im = pbase / 64;
            #pragma unroll
            for (int i = 0; i < 4; ++i)
                #pragma unroll
                for (int j = 0; j < 4; ++j) {
                    const int n = bn + wn0 + j * 16 + l16;
                    const float sc = gp[n] * 0.99999500003749969f;
                    const float bi = cbp[n] * sc + bep[n];
                    #pragma unroll
                    for (int rp = 0; rp < 2; ++rp) {
                        float xa = fmaxf(acc[i][j][2*rp]     * sc + bi, 0.f);
                        float xb = fmaxf(acc[i][j][2*rp + 1] * sc + bi, 0.f);
                        float xm = fmaxf(xa, xb);
                        float ym = fmaxf(xm, __shfl_xor(xm, 32));
                        if (lane < 32) {
                            const int py = i, px = (gq & 1) * 2 + rp;
                            long idx = ((long)(im * 4 + py) * 4 + px) * N + n;
                            ushort h = f2b(ym);
                            ((ushort*)O1)[idx] = h;
                            O2[idx] = f2b(ym - b2f(h));
                        }
                    }
                }
        }
    } else if constexpr (EPI == 4) {
        const int pbase = bm + wm0;
        const int im0 = pbase / 16;
        #pragma unroll
        for (int i = 0; i < 4; ++i)
            #pragma unroll
            for (int j = 0; j < 4; ++j) {
                const int n = bn + wn0 + j * 16 + l16;
                const float sc = gp[n] * 0.99999500003749969f;
                const float bi = cbp[n] * sc + bep[n];
                #pragma unroll
                for (int rp = 0; rp < 2; ++rp) {
                    float xa = fmaxf(acc[i][j][2*rp]     * sc + bi, 0.f);
                    float xb = fmaxf(acc[i][j][2*rp + 1] * sc + bi, 0.f);
                    float xm = fmaxf(xa, xb);
                    float ym = fmaxf(xm, __shfl_xor(xm, 16));
                    if ((gq & 1) == 0) {
                        const int py = gq >> 1, px = rp;
                        const long fi = (long)(im0 + i) * 2048 + (long)n * 4 + py * 2 + px;
                        ushort h = f2b(ym);
                        ((ushort*)O1)[fi] = h;
                        O2[fi] = f2b(ym - b2f(h));
                    }
                }
            }
    } else {
        #pragma unroll
        for (int i = 0; i < 4; ++i)
            #pragma unroll
            for (int j = 0; j < 4; ++j) {
                const int n = bn + wn0 + j * 16 + l16;
                const float bv = (n < realN) ? bias[n] : 0.f;
                #pragma unroll
                for (int r = 0; r < 4; ++r) {
                    const int m = bm + wm0 + i * 16 + gq * 4 + r;
                    float v = acc[i][j][r] + bv;
                    if (RELU) v = fmaxf(v, 0.f);
                    if constexpr (EPI == 1)
                        ((ushort*)O1 + (long)e * oStr)[(long)m * N + n] = f2b(v);
                    else
                        ((float*)O1 + (long)e * oStr)[(long)m * N + n] = v;
                }
            }
    }
}

// ---------------------------------------------------------------------------
// fused small GEMMs: clean[b][8], raw[b][8] from gh[b][4096]
// ---------------------------------------------------------------------------
__global__ __launch_bounds__(256) void small2_kernel(
    const float* __restrict__ gh, const float* __restrict__ wg2,
    const float* __restrict__ wg2b, const float* __restrict__ wn2,
    const float* __restrict__ wn2b, float* __restrict__ clean,
    float* __restrict__ rawp)
{
    const int b = blockIdx.x, tid = threadIdx.x;
    float ac[8] = {0,0,0,0,0,0,0,0}, ar[8] = {0,0,0,0,0,0,0,0};
    for (int k = tid; k < 2048; k += 256) {
        float a1 = gh[(long)b * 4096 + k];
        float a2 = gh[(long)b * 4096 + 2048 + k];
        const float4* w1 = (const float4*)&wg2[(long)k * 8];
        float4 p = w1[0], q = w1[1];
        ac[0] += a1 * p.x; ac[1] += a1 * p.y; ac[2] += a1 * p.z; ac[3] += a1 * p.w;
        ac[4] += a1 * q.x; ac[5] += a1 * q.y; ac[6] += a1 * q.z; ac[7] += a1 * q.w;
        const float4* w2 = (const float4*)&wn2[(long)k * 8];
        p = w2[0]; q = w2[1];
        ar[0] += a2 * p.x; ar[1] += a2 * p.y; ar[2] += a2 * p.z; ar[3] += a2 * p.w;
        ar[4] += a2 * q.x; ar[5] += a2 * q.y; ar[6] += a2 * q.z; ar[7] += a2 * q.w;
    }
    __shared__ float red[256][16];
    #pragma unroll
    for (int e2 = 0; e2 < 8; e2++) { red[tid][e2] = ac[e2]; red[tid][8 + e2] = ar[e2]; }
    __syncthreads();
    for (int s = 128; s > 0; s >>= 1) {
        if (tid < s)
            #pragma unroll
            for (int e2 = 0; e2 < 16; e2++) red[tid][e2] += red[tid + s][e2];
        __syncthreads();
    }
    if (tid < 8) clean[(long)b * 8 + tid] = red[0][tid] + wg2b[tid];
    else if (tid < 16) rawp[(long)b * 8 + tid - 8] = red[0][tid] + wn2b[tid - 8];
}

// ---------------------------------------------------------------------------
// gating: noisy top-k, softmax over top-K, gates, prob/load partials
// ---------------------------------------------------------------------------
__global__ __launch_bounds__(256) void gate_kernel(
    const float* __restrict__ clean, const float* __restrict__ raw,
    const float* __restrict__ noise, float* __restrict__ gates,
    float* __restrict__ part)
{
    __shared__ float red[256][8];
    const int tid = threadIdx.x;
    const int b = blockIdx.x * 256 + tid;

    float cl[8], st[8], ny[8];
    #pragma unroll
    for (int e2 = 0; e2 < 8; e2++) {
        cl[e2] = clean[(long)b * 8 + e2];
        float r = raw[(long)b * 8 + e2];
        st[e2] = fmaxf(r, 0.f) + log1pf(expf(-fabsf(r))) + 0.01f;
        ny[e2] = cl[e2] + noise[(long)b * 8 + e2] * st[e2];
    }
    float v0 = -3e38f, v1 = -3e38f, v2 = -3e38f;
    int i0 = 0, i1 = 0;
    #pragma unroll
    for (int e2 = 0; e2 < 8; e2++) {
        float xv = ny[e2];
        if (xv > v0)      { v2 = v1; v1 = v0; i1 = i0; v0 = xv; i0 = e2; }
        else if (xv > v1) { v2 = v1; v1 = xv; i1 = e2; }
        else if (xv > v2) { v2 = xv; }
    }
    float e1 = expf(v1 - v0);
    float z  = 1.f + e1;
    float g0 = 1.f / z, g1 = e1 / z;

    const float inv_sqrt2 = 0.70710678118654752f;
    float grow[8], prob[8];
    #pragma unroll
    for (int e2 = 0; e2 < 8; e2++) {
        grow[e2] = (e2 == i0) ? g0 : ((e2 == i1) ? g1 : 0.f);
        float th = (ny[e2] > v2) ? v2 : v1;
        float zz = (cl[e2] - th) / st[e2];
        prob[e2] = 0.5f * (1.f + erff(zz * inv_sqrt2));
        gates[(long)b * 8 + e2] = grow[e2];
    }
    #pragma unroll
    for (int e2 = 0; e2 < 8; e2++) red[tid][e2] = grow[e2];
    __syncthreads();
    for (int s = 128; s > 0; s >>= 1) {
        if (tid < s)
            #pragma unroll
            for (int e2 = 0; e2 < 8; e2++) red[tid][e2] += red[tid + s][e2];
        __syncthreads();
    }
    if (tid < 8) part[blockIdx.x * 16 + tid] = red[0][tid];
    __syncthreads();
    #pragma unroll
    for (int e2 = 0; e2 < 8; e2++) red[tid][e2] = prob[e2];
    __syncthreads();
    for (int s = 128; s > 0; s >>= 1) {
        if (tid < s)
            #pragma unroll
            for (int e2 = 0; e2 < 8; e2++) red[tid][e2] += red[tid + s][e2];
        __syncthreads();
    }
    if (tid < 8) part[blockIdx.x * 16 + 8 + tid] = red[0][tid];
}

__global__ void loss_kernel(const float* __restrict__ part, float* __restrict__ lossp)
{
    if (threadIdx.x == 0) {
        float imp[8], ld[8];
        for (int e2 = 0; e2 < 8; e2++) { imp[e2] = 0.f; ld[e2] = 0.f; }
        for (int blk = 0; blk < 8; blk++)
            for (int e2 = 0; e2 < 8; e2++) {
                imp[e2] += part[blk * 16 + e2];
                ld[e2]  += part[blk * 16 + 8 + e2];
            }
        float mi = 0.f, ml = 0.f;
        for (int e2 = 0; e2 < 8; e2++) { mi += imp[e2]; ml += ld[e2]; }
        mi *= 0.125f; ml *= 0.125f;
        float vi = 0.f, vl = 0.f;
        for (int e2 = 0; e2 < 8; e2++) {
            vi += (imp[e2] - mi) * (imp[e2] - mi);
            vl += (ld[e2] - ml) * (ld[e2] - ml);
        }
        vi /= 7.f; vl /= 7.f;
        lossp[0] = vi / (mi * mi + 1e-10f) + vl / (ml * ml + 1e-10f);
    }
}

__global__ void combine_kernel(const float* __restrict__ gates,
                               const float* __restrict__ eo, float* __restrict__ y)
{
    const int idx = blockIdx.x * 256 + threadIdx.x;
    if (idx >= BB * CC) return;
    const int b = idx / CC, c = idx % CC;
    float s = 0.f;
    #pragma unroll
    for (int e2 = 0; e2 < 8; e2++)
        s += gates[(long)b * 8 + e2] * eo[((long)e2 * BB + b) * 128 + c];
    y[idx] = s;
}

// ---------------------------------------------------------------------------
// launch
// ---------------------------------------------------------------------------
extern "C" void kernel_launch(void* const* d_in, const int* in_sizes, int n_in,
                              void* d_out, int out_size, void* d_ws, size_t ws_size,
                              hipStream_t stream)
{
    const float* x     = (const float*)d_in[0];
    const float* noise = (const float*)d_in[1];
    const float* cw1 = (const float*)d_in[2];  const float* cb1 = (const float*)d_in[3];
    const float* g1  = (const float*)d_in[4];  const float* be1 = (const float*)d_in[5];
    const float* cw2 = (const float*)d_in[6];  const float* cb2 = (const float*)d_in[7];
    const float* g2  = (const float*)d_in[8];  const float* be2 = (const float*)d_in[9];
    const float* cw3 = (const float*)d_in[10]; const float* cb3 = (const float*)d_in[11];
    const float* g3  = (const float*)d_in[12]; const float* be3 = (const float*)d_in[13];
    const float* cw4 = (const float*)d_in[14]; const float* cb4 = (const float*)d_in[15];
    const float* g4  = (const float*)d_in[16]; const float* be4 = (const float*)d_in[17];
    const float* wg1 = (const float*)d_in[18]; const float* wg1b = (const float*)d_in[19];
    const float* wg2 = (const float*)d_in[20]; const float* wg2b = (const float*)d_in[21];
    const float* wn1 = (const float*)d_in[22]; const float* wn1b = (const float*)d_in[23];
    const float* wn2 = (const float*)d_in[24]; const float* wn2b = (const float*)d_in[25];
    const float* eW1 = (const float*)d_in[26]; const float* eb1 = (const float*)d_in[27];
    const float* eW2 = (const float*)d_in[28]; const float* eb2 = (const float*)d_in[29];
    const float* eW3 = (const float*)d_in[30]; const float* eb3 = (const float*)d_in[31];

    float* out = (float*)d_out;
    char*  W   = (char*)d_ws;

    // ---- workspace layout (bytes), lifetime-overlaid, ~217 MB ----
    ushort* c2h   = (ushort*)(W + 0);              // [2048,16,16,64] hi (67.1MB)
    ushort* c2l   = (ushort*)(W + 67108864);       //                 lo
    ushort* c3h   = (ushort*)(W + 134217728);      // [2048,8,8,128] hi (33.5MB)
    ushort* c3l   = (ushort*)(W + 167772160);      //                 lo (ends 201326592)
    ushort* c4h   = (ushort*)(W + 0);              // [2048,4,4,256] hi (16.8MB, after conv3)
    ushort* c4l   = (ushort*)(W + 16777216);       //                 lo (ends 33554432)
    ushort* fh    = (ushort*)(W + 33554432);       // [2048,2048] bf16 hi
    ushort* fl    = (ushort*)(W + 41943040);       //              bf16 lo
    ushort* wTh   = (ushort*)(W + 50331648);       // [4096,2048] gating W^T hi (after conv2)
    ushort* wTl   = (ushort*)(W + 67108864);       //              lo
    float*  bias4096 = (float*)(W + 83886080);
    float*  gh    = (float*) (W + 83902464);       // [2048,4096] fp32 (ends 117456896)
    float*  clean = (float*) (W + 117456896);
    float*  rawp  = (float*) (W + 117522432);
    float*  gates = (float*) (W + 117587968);
    float*  part  = (float*) (W + 117653504);
    ushort* eW1T  = (ushort*)(W + 134217728);      // [8,1024,2048] (after conv3)
    ushort* eW2T  = (ushort*)(W + 167772160);      // [8,512,1024]
    ushort* eW3T  = (ushort*)(W + 176160768);      // [8,128,512]
    ushort* eh1   = (ushort*)(W + 177209344);      // [8,2048,1024] bf16 (ends 210763776)
    ushort* eh2   = (ushort*)(W + 83902464);       // [8,2048,512] bf16 (gh region, after small2)
    float*  eo    = (float*) (W + 0);              // [8,2048,128] fp32 (after conv4)
    ushort* bc2h  = (ushort*)(W + 210763776);      // conv-B packs
    ushort* bc2l  = (ushort*)(W + 210911232);
    ushort* bc3h  = (ushort*)(W + 211058688);
    ushort* bc3l  = (ushort*)(W + 211648512);
    ushort* bc4h  = (ushort*)(W + 212238336);
    ushort* bc4l  = (ushort*)(W + 214597632);      // ends 216956928

    // ---- zero used workspace (identical state every call) ----
    {
        long used = 216956928;
        long cap = (ws_size < (size_t)used) ? (long)ws_size : used;
        zero_ws_kernel<<<2048, 256, 0, stream>>>((int4*)d_ws, cap / 16);
    }

    // ---- conv weight packs ----
    prep_convw<<<(9 * 128 * 64 + 255) / 256, 256, 0, stream>>>(cw2, bc2h, bc2l, 128, 64);
    prep_convw<<<(9 * 256 * 128 + 255) / 256, 256, 0, stream>>>(cw3, bc3h, bc3l, 256, 128);
    prep_convw<<<(9 * 512 * 256 + 255) / 256, 256, 0, stream>>>(cw4, bc4h, bc4l, 512, 256);

    // ---- CNN ----
    conv1_kernel<<<2048, 256, 0, stream>>>(x, cw1, cb1, g1, be1, c2h, c2l);
    // conv2: M=524288, N=128, K=576
    mgemm<1, 3, true, false, 16, 64><<<dim3(4096, 1), 256, 0, stream>>>(
        c2h, c2l, nullptr, nullptr, bc2h, bc2l, nullptr, cb2, g2, be2,
        c3h, c3l, 524288, 128, 576, 128, 0, 0, 0, 0);

    // gating weight prep (c2 region now dead)
    prep_wT<true><<<dim3(64, 64, 1), 256, 0, stream>>>(wg1, wTh, wTl, 2048, 2048, 2048);
    prep_wT<true><<<dim3(64, 64, 1), 256, 0, stream>>>(wn1, wTh + 4194304, wTl + 4194304, 2048, 2048, 2048);
    prep_bias2<<<16, 256, 0, stream>>>(wg1b, wn1b, bias4096);

    // conv3: M=131072, N=256, K=1152
    mgemm<1, 3, true, false, 8, 128><<<dim3(1024, 2), 256, 0, stream>>>(
        c3h, c3l, nullptr, nullptr, bc3h, bc3l, nullptr, cb3, g3, be3,
        c4h, c4l, 131072, 256, 1152, 256, 0, 0, 0, 0);

    // expert weight prep (c3 region now dead)
    prep_wT<false><<<dim3(32, 64, 8), 256, 0, stream>>>(eW1, eW1T, nullptr, 2048, 1024, 1024);
    prep_wT<false><<<dim3(16, 32, 8), 256, 0, stream>>>(eW2, eW2T, nullptr, 1024, 512, 512);
    prep_wT<false><<<dim3(4, 16, 8), 256, 0, stream>>>(eW3, eW3T, nullptr, 512, 100, 128);

    // conv4: M=32768, N=512, K=2304 -> f hi/lo
    mgemm<1, 4, true, false, 4, 256><<<dim3(256, 4), 256, 0, stream>>>(
        c4h, c4l, nullptr, nullptr, bc4h, bc4l, nullptr, cb4, g4, be4,
        fh, fl, 32768, 512, 2304, 512, 0, 0, 0, 0);

    // ---- gating trunk (fused wg1|wn1, bf16x3) ----
    mgemm<0, 0, true, true, 1, 1><<<dim3(16, 32, 1), 256, 0, stream>>>(
        nullptr, nullptr, fh, fl, wTh, wTl, bias4096, nullptr, nullptr, nullptr,
        gh, nullptr, 2048, 4096, 2048, 4096, 0, 0, 0, 0);
    small2_kernel<<<BB, 256, 0, stream>>>(gh, wg2, wg2b, wn2, wn2b, clean, rawp);
    gate_kernel<<<8, 256, 0, stream>>>(clean, rawp, noise, gates, part);
    loss_kernel<<<1, 64, 0, stream>>>(part, out + (long)BB * CC);

    // ---- experts (plain bf16) ----
    mgemm<0, 1, false, true, 1, 1><<<dim3(16, 8, 8), 256, 0, stream>>>(
        nullptr, nullptr, fh, nullptr, eW1T, nullptr, eb1, nullptr, nullptr, nullptr,
        eh1, nullptr, 2048, 1024, 2048, 1024, 0, (long)1024 * 2048, 1024, (long)2048 * 1024);
    mgemm<0, 1, false, true, 1, 1><<<dim3(16, 4, 8), 256, 0, stream>>>(
        nullptr, nullptr, eh1, nullptr, eW2T, nullptr, eb2, nullptr, nullptr, nullptr,
        eh2, nullptr, 2048, 512, 1024, 512, (long)2048 * 1024, (long)512 * 1024, 512, (long)2048 * 512);
    mgemm<0, 2, false, false, 1, 1><<<dim3(16, 1, 8), 256, 0, stream>>>(
        nullptr, nullptr, eh2, nullptr, eW3T, nullptr, eb3, nullptr, nullptr, nullptr,
        eo, nullptr, 2048, 128, 512, 100, (long)2048 * 512, (long)128 * 512, 100, (long)2048 * 128);

    // ---- combine ----
    combine_kernel<<<(BB * CC + 255) / 256, 256, 0, stream>>>(gates, eo, out);
}

// Round 8
// 1570.522 us; speedup vs baseline: 2.7982x; 1.3576x over previous
//
#include <hip/hip_runtime.h>

#define BB 2048
#define EE 8
#define CC 100

typedef __attribute__((ext_vector_type(8))) short s16x8;
typedef __attribute__((ext_vector_type(4))) float f32x4;

__device__ inline ushort f2b(float f) {
    union { float f; unsigned u; } c; c.f = f;
    return (ushort)((c.u + 0x7fffu + ((c.u >> 16) & 1u)) >> 16);
}
__device__ inline float b2f(ushort h) {
    union { unsigned u; float f; } c; c.u = ((unsigned)h) << 16;
    return c.f;
}

// ---------------------------------------------------------------------------
// zero used workspace so every call starts from the identical state
// ---------------------------------------------------------------------------
__global__ __launch_bounds__(256) void zero_ws_kernel(int4* __restrict__ p, long n16)
{
    long i = (long)blockIdx.x * 256 + threadIdx.x;
    const long stride = (long)gridDim.x * 256;
    const int4 z = make_int4(0, 0, 0, 0);
    for (; i < n16; i += stride) p[i] = z;
}

// ---------------------------------------------------------------------------
// conv1: [2048,3,32,32] -> conv3x3+BN+ReLU+pool -> NHWC bf16 hi/lo [2048,16,16,64]
// ---------------------------------------------------------------------------
__global__ __launch_bounds__(256) void conv1_kernel(
    const float* __restrict__ x, const float* __restrict__ w,
    const float* __restrict__ cb, const float* __restrict__ g,
    const float* __restrict__ be, ushort* __restrict__ oh, ushort* __restrict__ ol)
{
    __shared__ float xs[3][34][34];
    __shared__ float wsm[64][28];
    __shared__ float sc_s[64], bi_s[64];

    const int b = blockIdx.x;
    const int tid = threadIdx.x;

    for (int i = tid; i < 3 * 34 * 34; i += 256) {
        int ci = i / (34 * 34);
        int r  = (i / 34) % 34;
        int c  = i % 34;
        float v = 0.f;
        if (r >= 1 && r <= 32 && c >= 1 && c <= 32)
            v = x[(((long)b * 3 + ci) * 32 + (r - 1)) * 32 + (c - 1)];
        xs[ci][r][c] = v;
    }
    for (int i = tid; i < 64 * 27; i += 256) {
        int co = i / 27, k = i % 27;
        wsm[co][k] = w[co * 27 + k];
    }
    if (tid < 64) {
        float s = g[tid] * 0.99999500003749969f;
        sc_s[tid] = s;
        bi_s[tid] = cb[tid] * s + be[tid];
    }
    __syncthreads();

    const int py = tid >> 4, px = tid & 15;
    float xr[3][4][4];
    #pragma unroll
    for (int ci = 0; ci < 3; ci++)
        #pragma unroll
        for (int r = 0; r < 4; r++)
            #pragma unroll
            for (int c = 0; c < 4; c++)
                xr[ci][r][c] = xs[ci][2 * py + r][2 * px + c];

    for (int co = 0; co < 64; co++) {
        float a0 = 0.f, a1 = 0.f, a2 = 0.f, a3 = 0.f;
        #pragma unroll
        for (int ci = 0; ci < 3; ci++)
            #pragma unroll
            for (int ky = 0; ky < 3; ky++)
                #pragma unroll
                for (int kx = 0; kx < 3; kx++) {
                    float wv = wsm[co][ci * 9 + ky * 3 + kx];
                    a0 += wv * xr[ci][ky][kx];
                    a1 += wv * xr[ci][ky][kx + 1];
                    a2 += wv * xr[ci][ky + 1][kx];
                    a3 += wv * xr[ci][ky + 1][kx + 1];
                }
        float s = sc_s[co], bb2 = bi_s[co];
        float v0 = fmaxf(a0 * s + bb2, 0.f);
        float v1 = fmaxf(a1 * s + bb2, 0.f);
        float v2 = fmaxf(a2 * s + bb2, 0.f);
        float v3 = fmaxf(a3 * s + bb2, 0.f);
        float v  = fmaxf(fmaxf(v0, v1), fmaxf(v2, v3));
        long o = (((long)b * 16 + py) * 16 + px) * 64 + co;
        ushort h = f2b(v);
        oh[o] = h;
        ol[o] = f2b(v - b2f(h));
    }
}

// ---------------------------------------------------------------------------
// prep: conv weights [CO][CI][3][3] fp32 -> [CO][s*CI+ci] bf16 hi/lo (GEMM-B)
// ---------------------------------------------------------------------------
__global__ void prep_convw(const float* __restrict__ w, ushort* __restrict__ oh,
                           ushort* __restrict__ ol, int CO, int CI)
{
    long total = (long)CO * CI * 9;
    long i = (long)blockIdx.x * 256 + threadIdx.x;
    if (i >= total) return;
    int co = (int)(i / (9 * CI));
    int rem = (int)(i % (9 * CI));
    int s = rem / CI, ci = rem % CI;
    float v = w[((long)co * CI + ci) * 9 + s];
    ushort h = f2b(v);
    long o = (long)co * (9 * CI) + (long)s * CI + ci;
    oh[o] = h;
    ol[o] = f2b(v - b2f(h));
}

// ---------------------------------------------------------------------------
// prep: [z][K][N] fp32 -> transposed [z][Npad][K] bf16 hi (+lo), zero-padded
// ---------------------------------------------------------------------------
template <bool SPLIT>
__global__ __launch_bounds__(256) void prep_wT(
    const float* __restrict__ in, ushort* __restrict__ oh, ushort* __restrict__ ol,
    int K, int N, int Npad)
{
    __shared__ float tile[32][33];
    const int b = blockIdx.z;
    in += (long)b * K * N;
    oh += (long)b * Npad * K;
    if (SPLIT) ol += (long)b * Npad * K;
    const int k0 = blockIdx.y * 32, n0 = blockIdx.x * 32;
    const int tx = threadIdx.x & 31, ty = threadIdx.x >> 5;
    for (int i = ty; i < 32; i += 8) {
        int k = k0 + i, n = n0 + tx;
        tile[i][tx] = (k < K && n < N) ? in[(long)k * N + n] : 0.f;
    }
    __syncthreads();
    for (int i = ty; i < 32; i += 8) {
        int n = n0 + i, k = k0 + tx;
        if (n < Npad && k < K) {
            float v = tile[tx][i];
            ushort h = f2b(v);
            oh[(long)n * K + k] = h;
            if (SPLIT) ol[(long)n * K + k] = f2b(v - b2f(h));
        }
    }
}

__global__ void prep_bias2(const float* __restrict__ a, const float* __restrict__ b,
                           float* __restrict__ o)
{
    int i = blockIdx.x * 256 + threadIdx.x;
    if (i < 2048) o[i] = a[i];
    else if (i < 4096) o[i] = b[i - 2048];
}

// ---------------------------------------------------------------------------
// mgemm: unified MFMA GEMM, 128x128 tile, BK=32, 4 waves, 4x4 16x16 frags.
// Staging is inline between the two barriers (R4 structure) — both reg-carried
// prefetch attempts (R5/R6) spilled acc+prefetch to scratch (~1.6 GB/dispatch
// HBM scratch traffic); at ~3 blocks/CU wave-TLP already hides HBM latency.
// ASRC 0: A = bf16 hi(/lo) [M][K].  ASRC 1: implicit im2col gather from
//   PRE-SPLIT NHWC bf16 hi/lo planes [nImg][S][S][CI], K = 9*CI (s-major) —
//   staging is pure int4 copies (no fp32->bf16 split VALU in the hot loop).
// ---------------------------------------------------------------------------
template <int ASRC, int EPI, bool SPLIT, bool RELU, int S, int CI>
__global__ __launch_bounds__(256) void mgemm(
    const ushort* __restrict__ Agh, const ushort* __restrict__ Agl,
    const ushort* __restrict__ Ah, const ushort* __restrict__ Al,
    const ushort* __restrict__ Bh, const ushort* __restrict__ Bl,
    const float* __restrict__ bias,
    const float* __restrict__ cbp, const float* __restrict__ gp,
    const float* __restrict__ bep,
    void* __restrict__ O1, ushort* __restrict__ O2,
    int M, int N, int K, int realN,
    long aStr, long bStr, long biasStr, long oStr)
{
    constexpr int BKp = 40;
    __shared__ ushort sAh[128 * BKp];
    __shared__ ushort sBh[128 * BKp];
    __shared__ ushort sAl[SPLIT ? 128 * BKp : 8];
    __shared__ ushort sBl[SPLIT ? 128 * BKp : 8];

    const int e = blockIdx.z;
    if constexpr (ASRC == 0) {
        Ah += (long)e * aStr;
        if (SPLIT) Al += (long)e * aStr;
    }
    Bh += (long)e * bStr;
    if (SPLIT) Bl += (long)e * bStr;
    bias += (long)e * biasStr;

    const int tid = threadIdx.x;
    const int bm = blockIdx.x * 128, bn = blockIdx.y * 128;
    const int lane = tid & 63, wid = tid >> 6;
    const int wm0 = (wid >> 1) * 64, wn0 = (wid & 1) * 64;
    const int l16 = lane & 15, gq = lane >> 4;
    const int koff = gq * 8;

    const int r0 = tid >> 2, cb = (tid & 3) * 8;     // ASRC0 + B staging
    const int sr = tid >> 1, scb = (tid & 1) * 16;   // ASRC1 staging

    int g_im = 0, g_y0 = 0, g_x0 = 0;
    if constexpr (ASRC == 1) {
        int p = bm + sr;
        g_im = p / (S * S);
        int rem = p % (S * S);
        g_y0 = rem / S;
        g_x0 = rem % S;
    }

    f32x4 acc[4][4];
    #pragma unroll
    for (int i = 0; i < 4; ++i)
        #pragma unroll
        for (int j = 0; j < 4; ++j)
            acc[i][j] = (f32x4){0.f, 0.f, 0.f, 0.f};

    for (int k0 = 0; k0 < K; k0 += 32) {
        __syncthreads();
        if constexpr (ASRC == 1) {
            const int s = k0 / CI, ci0 = k0 % CI;
            const int yy = g_y0 + s / 3 - 1, xx = g_x0 + (s % 3) - 1;
            const int o = sr * BKp + scb;
            if (yy >= 0 && yy < S && xx >= 0 && xx < S) {
                const long base = (((long)g_im * S + yy) * S + xx) * CI + ci0 + scb;
                *(int4*)&sAh[o]     = *(const int4*)&Agh[base];
                *(int4*)&sAh[o + 8] = *(const int4*)&Agh[base + 8];
                *(int4*)&sAl[o]     = *(const int4*)&Agl[base];
                *(int4*)&sAl[o + 8] = *(const int4*)&Agl[base + 8];
            } else {
                const int4 z = make_int4(0, 0, 0, 0);
                *(int4*)&sAh[o] = z; *(int4*)&sAh[o + 8] = z;
                *(int4*)&sAl[o] = z; *(int4*)&sAl[o + 8] = z;
            }
        } else {
            const int oa = r0 * BKp + cb;
            *(int4*)&sAh[oa]            = *(const int4*)&Ah[(long)(bm + r0) * K + k0 + cb];
            *(int4*)&sAh[oa + 64 * BKp] = *(const int4*)&Ah[(long)(bm + r0 + 64) * K + k0 + cb];
            if (SPLIT) {
                *(int4*)&sAl[oa]            = *(const int4*)&Al[(long)(bm + r0) * K + k0 + cb];
                *(int4*)&sAl[oa + 64 * BKp] = *(const int4*)&Al[(long)(bm + r0 + 64) * K + k0 + cb];
            }
        }
        {
            const int ob = r0 * BKp + cb;
            *(int4*)&sBh[ob]            = *(const int4*)&Bh[(long)(bn + r0) * K + k0 + cb];
            *(int4*)&sBh[ob + 64 * BKp] = *(const int4*)&Bh[(long)(bn + r0 + 64) * K + k0 + cb];
            if (SPLIT) {
                *(int4*)&sBl[ob]            = *(const int4*)&Bl[(long)(bn + r0) * K + k0 + cb];
                *(int4*)&sBl[ob + 64 * BKp] = *(const int4*)&Bl[(long)(bn + r0 + 64) * K + k0 + cb];
            }
        }
        __syncthreads();

        s16x8 fa[4], fb[4], fal[4], fbl[4];
        #pragma unroll
        for (int i = 0; i < 4; ++i) {
            fa[i] = *(const s16x8*)&sAh[(wm0 + i * 16 + l16) * BKp + koff];
            fb[i] = *(const s16x8*)&sBh[(wn0 + i * 16 + l16) * BKp + koff];
            if (SPLIT) {
                fal[i] = *(const s16x8*)&sAl[(wm0 + i * 16 + l16) * BKp + koff];
                fbl[i] = *(const s16x8*)&sBl[(wn0 + i * 16 + l16) * BKp + koff];
            }
        }
        #pragma unroll
        for (int i = 0; i < 4; ++i)
            #pragma unroll
            for (int j = 0; j < 4; ++j) {
                acc[i][j] = __builtin_amdgcn_mfma_f32_16x16x32_bf16(fa[i], fb[j], acc[i][j], 0, 0, 0);
                if (SPLIT) {
                    acc[i][j] = __builtin_amdgcn_mfma_f32_16x16x32_bf16(fa[i],  fbl[j], acc[i][j], 0, 0, 0);
                    acc[i][j] = __builtin_amdgcn_mfma_f32_16x16x32_bf16(fal[i], fb[j],  acc[i][j], 0, 0, 0);
                }
            }
    }

    if constexpr (EPI == 3) {
        const int pbase = bm + wm0;
        if constexpr (S == 16) {
            const int im = pbase / 256;
            const int yb = (pbase % 256) / 16;
            #pragma unroll
            for (int ip = 0; ip < 2; ++ip)
                #pragma unroll
                for (int j = 0; j < 4; ++j) {
                    const int n = bn + wn0 + j * 16 + l16;
                    const float sc = gp[n] * 0.99999500003749969f;
                    const float bi = cbp[n] * sc + bep[n];
                    #pragma unroll
                    for (int rp = 0; rp < 2; ++rp) {
                        float a00 = fmaxf(acc[2*ip][j][2*rp]     * sc + bi, 0.f);
                        float a01 = fmaxf(acc[2*ip][j][2*rp + 1] * sc + bi, 0.f);
                        float a10 = fmaxf(acc[2*ip+1][j][2*rp]     * sc + bi, 0.f);
                        float a11 = fmaxf(acc[2*ip+1][j][2*rp + 1] * sc + bi, 0.f);
                        float pv = fmaxf(fmaxf(a00, a01), fmaxf(a10, a11));
                        const int py = yb / 2 + ip;
                        const int px = gq * 2 + rp;
                        long idx = ((long)(im * 8 + py) * 8 + px) * N + n;
                        ushort h = f2b(pv);
                        ((ushort*)O1)[idx] = h;
                        O2[idx] = f2b(pv - b2f(h));
                    }
                }
        } else {  // S == 8
            const int im = pbase / 64;
            #pragma unroll
            for (int i = 0; i < 4; ++i)
                #pragma unroll
                for (int j = 0; j < 4; ++j) {
                    const int n = bn + wn0 + j * 16 + l16;
                    const float sc = gp[n] * 0.99999500003749969f;
                    const float bi = cbp[n] * sc + bep[n];
                    #pragma unroll
                    for (int rp = 0; rp < 2; ++rp) {
                        float xa = fmaxf(acc[i][j][2*rp]     * sc + bi, 0.f);
                        float xb = fmaxf(acc[i][j][2*rp + 1] * sc + bi, 0.f);
                        float xm = fmaxf(xa, xb);
                        float ym = fmaxf(xm, __shfl_xor(xm, 32));
                        if (lane < 32) {
                            const int py = i, px = (gq & 1) * 2 + rp;
                            long idx = ((long)(im * 4 + py) * 4 + px) * N + n;
                            ushort h = f2b(ym);
                            ((ushort*)O1)[idx] = h;
                            O2[idx] = f2b(ym - b2f(h));
                        }
                    }
                }
        }
    } else if constexpr (EPI == 4) {
        const int pbase = bm + wm0;
        const int im0 = pbase / 16;
        #pragma unroll
        for (int i = 0; i < 4; ++i)
            #pragma unroll
            for (int j = 0; j < 4; ++j) {
                const int n = bn + wn0 + j * 16 + l16;
                const float sc = gp[n] * 0.99999500003749969f;
                const float bi = cbp[n] * sc + bep[n];
                #pragma unroll
                for (int rp = 0; rp < 2; ++rp) {
                    float xa = fmaxf(acc[i][j][2*rp]     * sc + bi, 0.f);
                    float xb = fmaxf(acc[i][j][2*rp + 1] * sc + bi, 0.f);
                    float xm = fmaxf(xa, xb);
                    float ym = fmaxf(xm, __shfl_xor(xm, 16));
                    if ((gq & 1) == 0) {
                        const int py = gq >> 1, px = rp;
                        const long fi = (long)(im0 + i) * 2048 + (long)n * 4 + py * 2 + px;
                        ushort h = f2b(ym);
                        ((ushort*)O1)[fi] = h;
                        O2[fi] = f2b(ym - b2f(h));
                    }
                }
            }
    } else {
        #pragma unroll
        for (int i = 0; i < 4; ++i)
            #pragma unroll
            for (int j = 0; j < 4; ++j) {
                const int n = bn + wn0 + j * 16 + l16;
                const float bv = (n < realN) ? bias[n] : 0.f;
                #pragma unroll
                for (int r = 0; r < 4; ++r) {
                    const int m = bm + wm0 + i * 16 + gq * 4 + r;
                    float v = acc[i][j][r] + bv;
                    if (RELU) v = fmaxf(v, 0.f);
                    if constexpr (EPI == 1)
                        ((ushort*)O1 + (long)e * oStr)[(long)m * N + n] = f2b(v);
                    else
                        ((float*)O1 + (long)e * oStr)[(long)m * N + n] = v;
                }
            }
    }
}

// ---------------------------------------------------------------------------
// fused small GEMMs: clean[b][8], raw[b][8] from gh[b][4096]
// ---------------------------------------------------------------------------
__global__ __launch_bounds__(256) void small2_kernel(
    const float* __restrict__ gh, const float* __restrict__ wg2,
    const float* __restrict__ wg2b, const float* __restrict__ wn2,
    const float* __restrict__ wn2b, float* __restrict__ clean,
    float* __restrict__ rawp)
{
    const int b = blockIdx.x, tid = threadIdx.x;
    float ac[8] = {0,0,0,0,0,0,0,0}, ar[8] = {0,0,0,0,0,0,0,0};
    for (int k = tid; k < 2048; k += 256) {
        float a1 = gh[(long)b * 4096 + k];
        float a2 = gh[(long)b * 4096 + 2048 + k];
        const float4* w1 = (const float4*)&wg2[(long)k * 8];
        float4 p = w1[0], q = w1[1];
        ac[0] += a1 * p.x; ac[1] += a1 * p.y; ac[2] += a1 * p.z; ac[3] += a1 * p.w;
        ac[4] += a1 * q.x; ac[5] += a1 * q.y; ac[6] += a1 * q.z; ac[7] += a1 * q.w;
        const float4* w2 = (const float4*)&wn2[(long)k * 8];
        p = w2[0]; q = w2[1];
        ar[0] += a2 * p.x; ar[1] += a2 * p.y; ar[2] += a2 * p.z; ar[3] += a2 * p.w;
        ar[4] += a2 * q.x; ar[5] += a2 * q.y; ar[6] += a2 * q.z; ar[7] += a2 * q.w;
    }
    __shared__ float red[256][16];
    #pragma unroll
    for (int e2 = 0; e2 < 8; e2++) { red[tid][e2] = ac[e2]; red[tid][8 + e2] = ar[e2]; }
    __syncthreads();
    for (int s = 128; s > 0; s >>= 1) {
        if (tid < s)
            #pragma unroll
            for (int e2 = 0; e2 < 16; e2++) red[tid][e2] += red[tid + s][e2];
        __syncthreads();
    }
    if (tid < 8) clean[(long)b * 8 + tid] = red[0][tid] + wg2b[tid];
    else if (tid < 16) rawp[(long)b * 8 + tid - 8] = red[0][tid] + wn2b[tid - 8];
}

// ---------------------------------------------------------------------------
// gating: noisy top-k, softmax over top-K, gates, prob/load partials
// ---------------------------------------------------------------------------
__global__ __launch_bounds__(256) void gate_kernel(
    const float* __restrict__ clean, const float* __restrict__ raw,
    const float* __restrict__ noise, float* __restrict__ gates,
    float* __restrict__ part)
{
    __shared__ float red[256][8];
    const int tid = threadIdx.x;
    const int b = blockIdx.x * 256 + tid;

    float cl[8], st[8], ny[8];
    #pragma unroll
    for (int e2 = 0; e2 < 8; e2++) {
        cl[e2] = clean[(long)b * 8 + e2];
        float r = raw[(long)b * 8 + e2];
        st[e2] = fmaxf(r, 0.f) + log1pf(expf(-fabsf(r))) + 0.01f;
        ny[e2] = cl[e2] + noise[(long)b * 8 + e2] * st[e2];
    }
    float v0 = -3e38f, v1 = -3e38f, v2 = -3e38f;
    int i0 = 0, i1 = 0;
    #pragma unroll
    for (int e2 = 0; e2 < 8; e2++) {
        float xv = ny[e2];
        if (xv > v0)      { v2 = v1; v1 = v0; i1 = i0; v0 = xv; i0 = e2; }
        else if (xv > v1) { v2 = v1; v1 = xv; i1 = e2; }
        else if (xv > v2) { v2 = xv; }
    }
    float e1 = expf(v1 - v0);
    float z  = 1.f + e1;
    float g0 = 1.f / z, g1 = e1 / z;

    const float inv_sqrt2 = 0.70710678118654752f;
    float grow[8], prob[8];
    #pragma unroll
    for (int e2 = 0; e2 < 8; e2++) {
        grow[e2] = (e2 == i0) ? g0 : ((e2 == i1) ? g1 : 0.f);
        float th = (ny[e2] > v2) ? v2 : v1;
        float zz = (cl[e2] - th) / st[e2];
        prob[e2] = 0.5f * (1.f + erff(zz * inv_sqrt2));
        gates[(long)b * 8 + e2] = grow[e2];
    }
    #pragma unroll
    for (int e2 = 0; e2 < 8; e2++) red[tid][e2] = grow[e2];
    __syncthreads();
    for (int s = 128; s > 0; s >>= 1) {
        if (tid < s)
            #pragma unroll
            for (int e2 = 0; e2 < 8; e2++) red[tid][e2] += red[tid + s][e2];
        __syncthreads();
    }
    if (tid < 8) part[blockIdx.x * 16 + tid] = red[0][tid];
    __syncthreads();
    #pragma unroll
    for (int e2 = 0; e2 < 8; e2++) red[tid][e2] = prob[e2];
    __syncthreads();
    for (int s = 128; s > 0; s >>= 1) {
        if (tid < s)
            #pragma unroll
            for (int e2 = 0; e2 < 8; e2++) red[tid][e2] += red[tid + s][e2];
        __syncthreads();
    }
    if (tid < 8) part[blockIdx.x * 16 + 8 + tid] = red[0][tid];
}

__global__ void loss_kernel(const float* __restrict__ part, float* __restrict__ lossp)
{
    if (threadIdx.x == 0) {
        float imp[8], ld[8];
        for (int e2 = 0; e2 < 8; e2++) { imp[e2] = 0.f; ld[e2] = 0.f; }
        for (int blk = 0; blk < 8; blk++)
            for (int e2 = 0; e2 < 8; e2++) {
                imp[e2] += part[blk * 16 + e2];
                ld[e2]  += part[blk * 16 + 8 + e2];
            }
        float mi = 0.f, ml = 0.f;
        for (int e2 = 0; e2 < 8; e2++) { mi += imp[e2]; ml += ld[e2]; }
        mi *= 0.125f; ml *= 0.125f;
        float vi = 0.f, vl = 0.f;
        for (int e2 = 0; e2 < 8; e2++) {
            vi += (imp[e2] - mi) * (imp[e2] - mi);
            vl += (ld[e2] - ml) * (ld[e2] - ml);
        }
        vi /= 7.f; vl /= 7.f;
        lossp[0] = vi / (mi * mi + 1e-10f) + vl / (ml * ml + 1e-10f);
    }
}

__global__ void combine_kernel(const float* __restrict__ gates,
                               const float* __restrict__ eo, float* __restrict__ y)
{
    const int idx = blockIdx.x * 256 + threadIdx.x;
    if (idx >= BB * CC) return;
    const int b = idx / CC, c = idx % CC;
    float s = 0.f;
    #pragma unroll
    for (int e2 = 0; e2 < 8; e2++)
        s += gates[(long)b * 8 + e2] * eo[((long)e2 * BB + b) * 128 + c];
    y[idx] = s;
}

// ---------------------------------------------------------------------------
// launch
// ---------------------------------------------------------------------------
extern "C" void kernel_launch(void* const* d_in, const int* in_sizes, int n_in,
                              void* d_out, int out_size, void* d_ws, size_t ws_size,
                              hipStream_t stream)
{
    const float* x     = (const float*)d_in[0];
    const float* noise = (const float*)d_in[1];
    const float* cw1 = (const float*)d_in[2];  const float* cb1 = (const float*)d_in[3];
    const float* g1  = (const float*)d_in[4];  const float* be1 = (const float*)d_in[5];
    const float* cw2 = (const float*)d_in[6];  const float* cb2 = (const float*)d_in[7];
    const float* g2  = (const float*)d_in[8];  const float* be2 = (const float*)d_in[9];
    const float* cw3 = (const float*)d_in[10]; const float* cb3 = (const float*)d_in[11];
    const float* g3  = (const float*)d_in[12]; const float* be3 = (const float*)d_in[13];
    const float* cw4 = (const float*)d_in[14]; const float* cb4 = (const float*)d_in[15];
    const float* g4  = (const float*)d_in[16]; const float* be4 = (const float*)d_in[17];
    const float* wg1 = (const float*)d_in[18]; const float* wg1b = (const float*)d_in[19];
    const float* wg2 = (const float*)d_in[20]; const float* wg2b = (const float*)d_in[21];
    const float* wn1 = (const float*)d_in[22]; const float* wn1b = (const float*)d_in[23];
    const float* wn2 = (const float*)d_in[24]; const float* wn2b = (const float*)d_in[25];
    const float* eW1 = (const float*)d_in[26]; const float* eb1 = (const float*)d_in[27];
    const float* eW2 = (const float*)d_in[28]; const float* eb2 = (const float*)d_in[29];
    const float* eW3 = (const float*)d_in[30]; const float* eb3 = (const float*)d_in[31];

    float* out = (float*)d_out;
    char*  W   = (char*)d_ws;

    // ---- workspace layout (bytes), lifetime-overlaid, ~217 MB ----
    ushort* c2h   = (ushort*)(W + 0);              // [2048,16,16,64] hi (67.1MB)
    ushort* c2l   = (ushort*)(W + 67108864);       //                 lo
    ushort* c3h   = (ushort*)(W + 134217728);      // [2048,8,8,128] hi (33.5MB)
    ushort* c3l   = (ushort*)(W + 167772160);      //                 lo (ends 201326592)
    ushort* c4h   = (ushort*)(W + 0);              // [2048,4,4,256] hi (16.8MB, after conv3)
    ushort* c4l   = (ushort*)(W + 16777216);       //                 lo (ends 33554432)
    ushort* fh    = (ushort*)(W + 33554432);       // [2048,2048] bf16 hi
    ushort* fl    = (ushort*)(W + 41943040);       //              bf16 lo
    ushort* wTh   = (ushort*)(W + 50331648);       // [4096,2048] gating W^T hi (after conv2)
    ushort* wTl   = (ushort*)(W + 67108864);       //              lo
    float*  bias4096 = (float*)(W + 83886080);
    float*  gh    = (float*) (W + 83902464);       // [2048,4096] fp32 (ends 117456896)
    float*  clean = (float*) (W + 117456896);
    float*  rawp  = (float*) (W + 117522432);
    float*  gates = (float*) (W + 117587968);
    float*  part  = (float*) (W + 117653504);
    ushort* eW1T  = (ushort*)(W + 134217728);      // [8,1024,2048] (after conv3)
    ushort* eW2T  = (ushort*)(W + 167772160);      // [8,512,1024]
    ushort* eW3T  = (ushort*)(W + 176160768);      // [8,128,512]
    ushort* eh1   = (ushort*)(W + 177209344);      // [8,2048,1024] bf16 (ends 210763776)
    ushort* eh2   = (ushort*)(W + 83902464);       // [8,2048,512] bf16 (gh region, after small2)
    float*  eo    = (float*) (W + 0);              // [8,2048,128] fp32 (after conv4)
    ushort* bc2h  = (ushort*)(W + 210763776);      // conv-B packs
    ushort* bc2l  = (ushort*)(W + 210911232);
    ushort* bc3h  = (ushort*)(W + 211058688);
    ushort* bc3l  = (ushort*)(W + 211648512);
    ushort* bc4h  = (ushort*)(W + 212238336);
    ushort* bc4l  = (ushort*)(W + 214597632);      // ends 216956928

    // ---- zero used workspace (identical state every call) ----
    {
        long used = 216956928;
        long cap = (ws_size < (size_t)used) ? (long)ws_size : used;
        zero_ws_kernel<<<2048, 256, 0, stream>>>((int4*)d_ws, cap / 16);
    }

    // ---- conv weight packs ----
    prep_convw<<<(9 * 128 * 64 + 255) / 256, 256, 0, stream>>>(cw2, bc2h, bc2l, 128, 64);
    prep_convw<<<(9 * 256 * 128 + 255) / 256, 256, 0, stream>>>(cw3, bc3h, bc3l, 256, 128);
    prep_convw<<<(9 * 512 * 256 + 255) / 256, 256, 0, stream>>>(cw4, bc4h, bc4l, 512, 256);

    // ---- CNN ----
    conv1_kernel<<<2048, 256, 0, stream>>>(x, cw1, cb1, g1, be1, c2h, c2l);
    // conv2: M=524288, N=128, K=576
    mgemm<1, 3, true, false, 16, 64><<<dim3(4096, 1), 256, 0, stream>>>(
        c2h, c2l, nullptr, nullptr, bc2h, bc2l, nullptr, cb2, g2, be2,
        c3h, c3l, 524288, 128, 576, 128, 0, 0, 0, 0);

    // gating weight prep (c2 region now dead)
    prep_wT<true><<<dim3(64, 64, 1), 256, 0, stream>>>(wg1, wTh, wTl, 2048, 2048, 2048);
    prep_wT<true><<<dim3(64, 64, 1), 256, 0, stream>>>(wn1, wTh + 4194304, wTl + 4194304, 2048, 2048, 2048);
    prep_bias2<<<16, 256, 0, stream>>>(wg1b, wn1b, bias4096);

    // conv3: M=131072, N=256, K=1152
    mgemm<1, 3, true, false, 8, 128><<<dim3(1024, 2), 256, 0, stream>>>(
        c3h, c3l, nullptr, nullptr, bc3h, bc3l, nullptr, cb3, g3, be3,
        c4h, c4l, 131072, 256, 1152, 256, 0, 0, 0, 0);

    // expert weight prep (c3 region now dead)
    prep_wT<false><<<dim3(32, 64, 8), 256, 0, stream>>>(eW1, eW1T, nullptr, 2048, 1024, 1024);
    prep_wT<false><<<dim3(16, 32, 8), 256, 0, stream>>>(eW2, eW2T, nullptr, 1024, 512, 512);
    prep_wT<false><<<dim3(4, 16, 8), 256, 0, stream>>>(eW3, eW3T, nullptr, 512, 100, 128);

    // conv4: M=32768, N=512, K=2304 -> f hi/lo
    mgemm<1, 4, true, false, 4, 256><<<dim3(256, 4), 256, 0, stream>>>(
        c4h, c4l, nullptr, nullptr, bc4h, bc4l, nullptr, cb4, g4, be4,
        fh, fl, 32768, 512, 2304, 512, 0, 0, 0, 0);

    // ---- gating trunk (fused wg1|wn1, bf16x3) ----
    mgemm<0, 0, true, true, 1, 1><<<dim3(16, 32, 1), 256, 0, stream>>>(
        nullptr, nullptr, fh, fl, wTh, wTl, bias4096, nullptr, nullptr, nullptr,
        gh, nullptr, 2048, 4096, 2048, 4096, 0, 0, 0, 0);
    small2_kernel<<<BB, 256, 0, stream>>>(gh, wg2, wg2b, wn2, wn2b, clean, rawp);
    gate_kernel<<<8, 256, 0, stream>>>(clean, rawp, noise, gates, part);
    loss_kernel<<<1, 64, 0, stream>>>(part, out + (long)BB * CC);

    // ---- experts (plain bf16) ----
    mgemm<0, 1, false, true, 1, 1><<<dim3(16, 8, 8), 256, 0, stream>>>(
        nullptr, nullptr, fh, nullptr, eW1T, nullptr, eb1, nullptr, nullptr, nullptr,
        eh1, nullptr, 2048, 1024, 2048, 1024, 0, (long)1024 * 2048, 1024, (long)2048 * 1024);
    mgemm<0, 1, false, true, 1, 1><<<dim3(16, 4, 8), 256, 0, stream>>>(
        nullptr, nullptr, eh1, nullptr, eW2T, nullptr, eb2, nullptr, nullptr, nullptr,
        eh2, nullptr, 2048, 512, 1024, 512, (long)2048 * 1024, (long)512 * 1024, 512, (long)2048 * 512);
    mgemm<0, 2, false, false, 1, 1><<<dim3(16, 1, 8), 256, 0, stream>>>(
        nullptr, nullptr, eh2, nullptr, eW3T, nullptr, eb3, nullptr, nullptr, nullptr,
        eo, nullptr, 2048, 128, 512, 100, (long)2048 * 512, (long)128 * 512, 100, (long)2048 * 128);

    // ---- combine ----
    combine_kernel<<<(BB * CC + 255) / 256, 256, 0, stream>>>(gates, eo, out);
}